// Round 5
// baseline (805.739 us; speedup 1.0000x reference)
//
#include <hip/hip_runtime.h>
#include <stdint.h>

#define NN 100000   // nodes
#define NE 800000   // edges
#define NG 4000     // graphs
#define NBLK ((NN + 255) / 256)   // 391 scan blocks

typedef __attribute__((ext_vector_type(8))) short s16x8;   // 8 bf16 (4 VGPRs)
typedef __attribute__((ext_vector_type(4))) float f32x4;

__device__ __forceinline__ float b2f(unsigned short u) {
    return __uint_as_float(((unsigned int)u) << 16);
}
__device__ __forceinline__ unsigned short f2b(float f) {
    unsigned int x = __float_as_uint(f);
    x = x + 0x7FFFu + ((x >> 16) & 1u);   // RNE
    return (unsigned short)(x >> 16);
}
__device__ __forceinline__ s16x8 cvt8(const float* __restrict__ p) {
    float4 a = *(const float4*)p;
    float4 b = *(const float4*)(p + 4);
    s16x8 r = {(short)f2b(a.x), (short)f2b(a.y), (short)f2b(a.z), (short)f2b(a.w),
               (short)f2b(b.x), (short)f2b(b.y), (short)f2b(b.z), (short)f2b(b.w)};
    return r;
}

// async global->LDS, 16B per lane. LDS dest = wave-uniform base + lane*16.
__device__ __forceinline__ void gload16(const void* g, void* l) {
    __builtin_amdgcn_global_load_lds((const __attribute__((address_space(1))) unsigned int*)g,
                                     (__attribute__((address_space(3))) unsigned int*)l, 16, 0, 0);
}

// ---------------- degree / CSR build ----------------
__global__ void k_count(const int* __restrict__ dst, int* __restrict__ cnt) {
    int e = blockIdx.x * 256 + threadIdx.x;
    if (e < NE) atomicAdd(&cnt[dst[e]], 1);
}

__global__ void k_dinv(const int* __restrict__ cnt, float* __restrict__ dinv) {
    int n = blockIdx.x * 256 + threadIdx.x;
    if (n < NN) dinv[n] = rsqrtf((float)(cnt[n] + 1));  // +1 self loop
}

__global__ __launch_bounds__(256) void k_bsum(const int* __restrict__ cnt, int* __restrict__ bsum) {
    __shared__ int s[256];
    int i = blockIdx.x * 256 + threadIdx.x;
    s[threadIdx.x] = (i < NN) ? cnt[i] : 0;
    __syncthreads();
    for (int off = 128; off; off >>= 1) {
        if (threadIdx.x < off) s[threadIdx.x] += s[threadIdx.x + off];
        __syncthreads();
    }
    if (threadIdx.x == 0) bsum[blockIdx.x] = s[0];
}

__global__ __launch_bounds__(512) void k_bscan(const int* __restrict__ bsum, int* __restrict__ bpre) {
    __shared__ int s[512];
    int t = threadIdx.x;
    int v = (t < NBLK) ? bsum[t] : 0;
    s[t] = v;
    __syncthreads();
    for (int off = 1; off < 512; off <<= 1) {
        int u = (t >= off) ? s[t - off] : 0;
        __syncthreads();
        s[t] += u;
        __syncthreads();
    }
    if (t < NBLK) bpre[t] = s[t] - v;   // exclusive prefix of block sums
}

__global__ __launch_bounds__(256) void k_rowptr(const int* __restrict__ cnt, const int* __restrict__ bpre,
                                                int* __restrict__ row_ptr, int* __restrict__ cursor) {
    __shared__ int s[256];
    int t = threadIdx.x;
    int i = blockIdx.x * 256 + t;
    int v = (i < NN) ? cnt[i] : 0;
    s[t] = v;
    __syncthreads();
    for (int off = 1; off < 256; off <<= 1) {
        int u = (t >= off) ? s[t - off] : 0;
        __syncthreads();
        s[t] += u;
        __syncthreads();
    }
    if (i < NN) {
        int excl = bpre[blockIdx.x] + s[t] - v;
        row_ptr[i] = excl;
        cursor[i] = excl;
        if (i == NN - 1) row_ptr[NN] = NE;
    }
}

__global__ void k_fill(const int* __restrict__ src, const int* __restrict__ dst,
                       int* __restrict__ cursor, int* __restrict__ colA) {
    int e = blockIdx.x * 256 + threadIdx.x;
    if (e < NE) {
        int d = dst[e];
        int p = atomicAdd(&cursor[d], 1);
        colA[p] = src[e];
    }
}

// ---------------- weight transpose-convert: src f32 [K][N] -> dst bf16 [N][K] ----------------
__global__ void k_t(const float* __restrict__ src, unsigned short* __restrict__ dst, int KN, int ln) {
    int i = blockIdx.x * 256 + threadIdx.x;
    if (i < KN) {
        int k = i >> ln, n = i & ((1 << ln) - 1);
        dst[(size_t)n * (KN >> ln) + k] = f2b(src[i]);
    }
}

// fingerprint f32 -> bf16 (no transpose), 8 elems/thread
__global__ void k_cvt(const float* __restrict__ src, unsigned short* __restrict__ dst, int n8) {
    int i = blockIdx.x * 256 + threadIdx.x;
    if (i < n8) *(s16x8*)&dst[(size_t)i * 8] = cvt8(&src[(size_t)i * 8]);
}

// init fp_emb with bias (split-K GEMM accumulates on top)
__global__ void k_binit(float* __restrict__ fe, const float* __restrict__ b) {
    int i = blockIdx.x * 256 + threadIdx.x;   // NG*256 threads
    fe[i] = b[i & 255];
}

// fp_emb f32 -> zcat bf16 (cols 0..255 of [NG][512])
__global__ void k_z(const float* __restrict__ fe, unsigned short* __restrict__ zcat) {
    int i = blockIdx.x * 256 + threadIdx.x;   // NG*256 threads
    int g = i >> 8, c = i & 255;
    zcat[(size_t)g * 512 + c] = f2b(fe[i]);
}

// ---------------- reg-staged MFMA GEMM with embedding gather (projector layer 1) ----------------
template <bool GATHER, bool BIAS, bool RELU, bool CBF16>
__global__ __launch_bounds__(256) void k_mm(
    const unsigned short* __restrict__ A, const unsigned short* __restrict__ Bt,
    void* __restrict__ Cv, const float* __restrict__ bias, int M, int N, int K,
    const int* __restrict__ ai, const int* __restrict__ di, const int* __restrict__ ci,
    const float* __restrict__ ea, const float* __restrict__ ed, const float* __restrict__ ec) {
    __shared__ unsigned short As[128 * 40];   // stride 40 shorts: 2-way bank alias = free
    __shared__ unsigned short Bs[128 * 40];
    const int tid = threadIdx.x;
    const int row0 = blockIdx.x * 128, col0 = blockIdx.y * 128;
    const int lane = tid & 63, wid = tid >> 6;
    const int wrow = (wid >> 1) * 64, wcol = (wid & 1) * 64;
    const int lr = lane & 15, lk8 = (lane >> 4) * 8;

    const int sr = tid >> 1;          // staging row 0..127
    const int skc = (tid & 1) * 16;   // staging k offset {0,16}
    const int agrow = row0 + sr;
    const int bgrow = col0 + sr;
    int ia = 0, idg = 0, ic = 0;
    if (GATHER && agrow < M) { ia = ai[agrow] * 128; idg = di[agrow] * 128; ic = ci[agrow] * 128; }

    f32x4 acc[4][4] = {};

    for (int kb = 0; kb < K; kb += 32) {
        if (kb) __syncthreads();
#pragma unroll
        for (int c = 0; c < 2; ++c) {
            int kloc = skc + c * 8;
            s16x8 v = {};
            if (agrow < M) {
                if (GATHER) {
                    int kg = kb + kloc;
                    const float* p = (kg < 128) ? (ea + ia + kg)
                                   : (kg < 256) ? (ed + idg + kg - 128)
                                                : (ec + ic + kg - 256);
                    v = cvt8(p);
                } else {
                    v = *(const s16x8*)&A[(size_t)agrow * K + kb + kloc];
                }
            }
            *(s16x8*)&As[sr * 40 + kloc] = v;
            s16x8 w = *(const s16x8*)&Bt[(size_t)bgrow * K + kb + kloc];
            *(s16x8*)&Bs[sr * 40 + kloc] = w;
        }
        __syncthreads();
        s16x8 af[4], bfr[4];
#pragma unroll
        for (int f = 0; f < 4; ++f)
            af[f] = *(const s16x8*)&As[(wrow + f * 16 + lr) * 40 + lk8];
#pragma unroll
        for (int f = 0; f < 4; ++f)
            bfr[f] = *(const s16x8*)&Bs[(wcol + f * 16 + lr) * 40 + lk8];
#pragma unroll
        for (int fm = 0; fm < 4; ++fm)
#pragma unroll
            for (int fn = 0; fn < 4; ++fn)
                acc[fm][fn] = __builtin_amdgcn_mfma_f32_16x16x32_bf16(af[fm], bfr[fn], acc[fm][fn], 0, 0, 0);
    }
#pragma unroll
    for (int fm = 0; fm < 4; ++fm) {
#pragma unroll
        for (int r = 0; r < 4; ++r) {
            int row = row0 + wrow + fm * 16 + (lane >> 4) * 4 + r;
            if (row < M) {
#pragma unroll
                for (int fn = 0; fn < 4; ++fn) {
                    int col = col0 + wcol + fn * 16 + lr;
                    float v = acc[fm][fn][r];
                    if (BIAS) v += bias[col];
                    if (RELU) v = fmaxf(v, 0.f);
                    if (CBF16) ((unsigned short*)Cv)[(size_t)row * N + col] = f2b(v);
                    else       ((float*)Cv)[(size_t)row * N + col] = v;
                }
            }
        }
    }
}

// ---------------- m97-style MFMA GEMM: global_load_lds staging, linear LDS [128][32] ----------------
// A bf16 [M][K] row-major, Bt bf16 [N][K] row-major (K%32==0, N%128==0).
// SPLITK: blockIdx.z selects K-chunk of size kc; f32 atomicAdd epilogue (no bias/relu).
template <bool BIAS, bool RELU, bool CBF16, bool SPLITK>
__global__ __launch_bounds__(256) void k_mmA(
    const unsigned short* __restrict__ A, const unsigned short* __restrict__ Bt,
    void* __restrict__ Cv, const float* __restrict__ bias, int M, int N, int K, int kc) {
    __shared__ unsigned short As[128 * 32];
    __shared__ unsigned short Bs[128 * 32];
    const int tid = threadIdx.x;
    const int row0 = blockIdx.x * 128, col0 = blockIdx.y * 128;
    const int lane = tid & 63, wid = tid >> 6;
    const int wrow = (wid >> 1) * 64, wcol = (wid & 1) * 64;
    const int lr = lane & 15, lk8 = (lane >> 4) * 8;

    const int k0 = SPLITK ? blockIdx.z * kc : 0;
    const int k1 = SPLITK ? k0 + kc : K;

    // staging: wave wid covers LDS rows [wid*32, wid*32+32) in two 1KB chunks.
    // lane l of a chunk: row += l/4, col8 = (l&3)*8  (LDS byte = l*16, row stride 64B)
    const int sra = wid * 32 + (lane >> 2);
    const int sca = (lane & 3) * 8;
    const unsigned short* a0 = A + (size_t)min(row0 + sra, M - 1) * K + sca;
    const unsigned short* a1 = A + (size_t)min(row0 + sra + 16, M - 1) * K + sca;
    const unsigned short* b0 = Bt + (size_t)(col0 + sra) * K + sca;
    const unsigned short* b1 = Bt + (size_t)(col0 + sra + 16) * K + sca;
    unsigned short* lA0 = &As[(wid * 2 + 0) * 512];
    unsigned short* lA1 = &As[(wid * 2 + 1) * 512];
    unsigned short* lB0 = &Bs[(wid * 2 + 0) * 512];
    unsigned short* lB1 = &Bs[(wid * 2 + 1) * 512];

    f32x4 acc[4][4] = {};

    for (int kb = k0; kb < k1; kb += 32) {
        if (kb != k0) __syncthreads();
        gload16(a0 + kb, lA0);
        gload16(a1 + kb, lA1);
        gload16(b0 + kb, lB0);
        gload16(b1 + kb, lB1);
        __syncthreads();   // compiler drains vmcnt before s_barrier
        s16x8 af[4], bfr[4];
#pragma unroll
        for (int f = 0; f < 4; ++f)
            af[f] = *(const s16x8*)&As[(wrow + f * 16 + lr) * 32 + lk8];
#pragma unroll
        for (int f = 0; f < 4; ++f)
            bfr[f] = *(const s16x8*)&Bs[(wcol + f * 16 + lr) * 32 + lk8];
#pragma unroll
        for (int fm = 0; fm < 4; ++fm)
#pragma unroll
            for (int fn = 0; fn < 4; ++fn)
                acc[fm][fn] = __builtin_amdgcn_mfma_f32_16x16x32_bf16(af[fm], bfr[fn], acc[fm][fn], 0, 0, 0);
    }
#pragma unroll
    for (int fm = 0; fm < 4; ++fm) {
#pragma unroll
        for (int r = 0; r < 4; ++r) {
            int row = row0 + wrow + fm * 16 + (lane >> 4) * 4 + r;
            if (row < M) {
#pragma unroll
                for (int fn = 0; fn < 4; ++fn) {
                    int col = col0 + wcol + fn * 16 + lr;
                    float v = acc[fm][fn][r];
                    if (SPLITK) {
                        atomicAdd(&((float*)Cv)[(size_t)row * N + col], v);
                    } else {
                        if (BIAS) v += bias[col];
                        if (RELU) v = fmaxf(v, 0.f);
                        if (CBF16) ((unsigned short*)Cv)[(size_t)row * N + col] = f2b(v);
                        else       ((float*)Cv)[(size_t)row * N + col] = v;
                    }
                }
            }
        }
    }
}

// ---------------- GCN aggregate, W=128 (one wave per node, 4 edges in flight) ----------------
template <int W, bool FUSE>
__global__ __launch_bounds__(256) void k_scat(const unsigned short* __restrict__ xw,
                                              unsigned short* __restrict__ hout,
                                              const float* __restrict__ dinv,
                                              const int* __restrict__ row_ptr,
                                              const int* __restrict__ colA,
                                              const float* __restrict__ bias) {
    constexpr int RPW = 1024 / W;
    constexpr int G = 64 / RPW;
    const int wid = threadIdx.x >> 6, lane = threadIdx.x & 63;
    const int v = blockIdx.x * 4 + wid;
    const int grp = lane / G, li = lane % G;
    const int c0 = li * 8;
    const float dv = dinv[v];
    float acc[8] = {};
    const int beg = row_ptr[v], end = row_ptr[v + 1];
    int p = beg + grp;
    for (; p + RPW < end; p += 2 * RPW) {
        int s0 = colA[p], s1 = colA[p + RPW];
        float w0 = dinv[s0] * dv, w1 = dinv[s1] * dv;
        s16x8 r0 = *(const s16x8*)&xw[(size_t)s0 * W + c0];
        s16x8 r1 = *(const s16x8*)&xw[(size_t)s1 * W + c0];
#pragma unroll
        for (int j = 0; j < 8; ++j) acc[j] = fmaf(b2f((unsigned short)r0[j]), w0, acc[j]);
#pragma unroll
        for (int j = 0; j < 8; ++j) acc[j] = fmaf(b2f((unsigned short)r1[j]), w1, acc[j]);
    }
    if (p < end) {
        int s0 = colA[p];
        float w0 = dinv[s0] * dv;
        s16x8 r0 = *(const s16x8*)&xw[(size_t)s0 * W + c0];
#pragma unroll
        for (int j = 0; j < 8; ++j) acc[j] = fmaf(b2f((unsigned short)r0[j]), w0, acc[j]);
    }
#pragma unroll
    for (int j = 0; j < 8; ++j) {
        if (RPW == 4) acc[j] += __shfl_xor(acc[j], 16);
        acc[j] += __shfl_xor(acc[j], 32);
    }
    s16x8 rs = *(const s16x8*)&xw[(size_t)v * W + c0];
    const float ws = dv * dv;
    unsigned short o[8];
#pragma unroll
    for (int j = 0; j < 8; ++j) {
        float x = fmaf(b2f((unsigned short)rs[j]), ws, acc[j]);
        if (FUSE) x = fmaxf(x + bias[c0 + j], 0.f);
        o[j] = f2b(x);
    }
    if (grp == 0) *(s16x8*)&hout[(size_t)v * W + c0] = *(const s16x8*)o;
}

// ---------------- GCN aggregate, W=256, column-sliced: 2 waves/node, 4 edges in flight each ----------------
__global__ __launch_bounds__(256) void k_scat256(const unsigned short* __restrict__ xw,
                                                 unsigned short* __restrict__ hout,
                                                 const float* __restrict__ dinv,
                                                 const int* __restrict__ row_ptr,
                                                 const int* __restrict__ colA,
                                                 const float* __restrict__ bias) {
    const int wid = threadIdx.x >> 6, lane = threadIdx.x & 63;
    const int v = blockIdx.x * 2 + (wid >> 1);   // NN % 2 == 0
    const int cs = (wid & 1) * 128;              // column slice
    const int grp = lane >> 4, li = lane & 15;
    const int c0 = cs + li * 8;
    const float dv = dinv[v];
    float acc[8] = {};
    const int beg = row_ptr[v], end = row_ptr[v + 1];
    int p = beg + grp;
    for (; p + 4 < end; p += 8) {
        int s0 = colA[p], s1 = colA[p + 4];
        float w0 = dinv[s0] * dv, w1 = dinv[s1] * dv;
        s16x8 r0 = *(const s16x8*)&xw[(size_t)s0 * 256 + c0];
        s16x8 r1 = *(const s16x8*)&xw[(size_t)s1 * 256 + c0];
#pragma unroll
        for (int j = 0; j < 8; ++j) acc[j] = fmaf(b2f((unsigned short)r0[j]), w0, acc[j]);
#pragma unroll
        for (int j = 0; j < 8; ++j) acc[j] = fmaf(b2f((unsigned short)r1[j]), w1, acc[j]);
    }
    if (p < end) {
        int s0 = colA[p];
        float w0 = dinv[s0] * dv;
        s16x8 r0 = *(const s16x8*)&xw[(size_t)s0 * 256 + c0];
#pragma unroll
        for (int j = 0; j < 8; ++j) acc[j] = fmaf(b2f((unsigned short)r0[j]), w0, acc[j]);
    }
#pragma unroll
    for (int j = 0; j < 8; ++j) {
        acc[j] += __shfl_xor(acc[j], 16);
        acc[j] += __shfl_xor(acc[j], 32);
    }
    s16x8 rs = *(const s16x8*)&xw[(size_t)v * 256 + c0];
    const float ws = dv * dv;
    unsigned short o[8];
#pragma unroll
    for (int j = 0; j < 8; ++j) {
        float x = fmaf(b2f((unsigned short)rs[j]), ws, acc[j]);
        x = fmaxf(x + bias[c0 + j], 0.f);
        o[j] = f2b(x);
    }
    if (grp == 0) *(s16x8*)&hout[(size_t)v * 256 + c0] = *(const s16x8*)o;
}

// ---------------- graph boundaries from sorted batch ----------------
__global__ void k_bounds(const int* __restrict__ batch, int* __restrict__ gstart) {
    int n = blockIdx.x * 256 + threadIdx.x;
    if (n >= NN) return;
    int b = batch[n];
    if (n == 0) {
        for (int g = 0; g <= b; ++g) gstart[g] = 0;
    } else {
        int pb = batch[n - 1];
        if (pb != b)
            for (int g = pb + 1; g <= b; ++g) gstart[g] = n;
    }
    if (n == NN - 1) {
        for (int g = b + 1; g <= NG; ++g) gstart[g] = NN;
    }
}

// ---------------- pooling: bf16 sums into zcat cols 256..511 ----------------
__global__ __launch_bounds__(64) void k_pool(const unsigned short* __restrict__ h,
                                             const int* __restrict__ gstart,
                                             unsigned short* __restrict__ zcat) {
    int g = blockIdx.x;
    int lane = threadIdx.x;
    int c0 = lane * 4;
    int beg = gstart[g], end = gstart[g + 1];
    float a0 = 0.f, a1 = 0.f, a2 = 0.f, a3 = 0.f;
    for (int n = beg; n < end; ++n) {
        ushort4 r = *(const ushort4*)&h[(size_t)n * 256 + c0];
        a0 += b2f(r.x); a1 += b2f(r.y); a2 += b2f(r.z); a3 += b2f(r.w);
    }
    ushort4 o;
    o.x = f2b(a0); o.y = f2b(a1); o.z = f2b(a2); o.w = f2b(a3);
    *(ushort4*)&zcat[(size_t)g * 512 + 256 + c0] = o;
}

// ---------------- final dot: out[g] = z1[g] . w2 + b2 ----------------
__global__ __launch_bounds__(256) void k_dot(const float* __restrict__ z1,
                                             const float* __restrict__ w2,
                                             const float* __restrict__ b2,
                                             float* __restrict__ out) {
    int wid = threadIdx.x >> 6, lane = threadIdx.x & 63;
    int g = blockIdx.x * 4 + wid;   // NG % 4 == 0
    float s = z1[(size_t)g * 128 + lane] * w2[lane]
            + z1[(size_t)g * 128 + 64 + lane] * w2[64 + lane];
#pragma unroll
    for (int off = 32; off; off >>= 1) s += __shfl_xor(s, off);
    if (lane == 0) out[g] = s + b2[0];
}

// ---------------- launch ----------------
extern "C" void kernel_launch(void* const* d_in, const int* in_sizes, int n_in,
                              void* d_out, int out_size, void* d_ws, size_t ws_size,
                              hipStream_t stream) {
    const int* atom_idx   = (const int*)d_in[0];
    const int* degree_idx = (const int*)d_in[1];
    const int* charge_idx = (const int*)d_in[2];
    const int* edge_index = (const int*)d_in[3];
    const int* batch      = (const int*)d_in[4];
    const float* fingerprint = (const float*)d_in[5];
    const float* emb_atom   = (const float*)d_in[6];
    const float* emb_degree = (const float*)d_in[7];
    const float* emb_charge = (const float*)d_in[8];
    const float* proj_w1 = (const float*)d_in[9];
    const float* proj_b1 = (const float*)d_in[10];
    const float* proj_w2 = (const float*)d_in[11];
    const float* proj_b2 = (const float*)d_in[12];
    const float* fp_w = (const float*)d_in[13];
    const float* fp_b = (const float*)d_in[14];
    const float* conv_w[4] = {(const float*)d_in[15], (const float*)d_in[17],
                              (const float*)d_in[19], (const float*)d_in[21]};
    const float* conv_b[4] = {(const float*)d_in[16], (const float*)d_in[18],
                              (const float*)d_in[20], (const float*)d_in[22]};
    const float* lin1_w = (const float*)d_in[23];
    const float* lin1_b = (const float*)d_in[24];
    const float* lin2_w = (const float*)d_in[25];
    const float* lin2_b = (const float*)d_in[26];
    float* out = (float*)d_out;

    const int* src = edge_index;
    const int* dst = edge_index + NE;

    // workspace carve (256B aligned)
    char* p = (char*)d_ws;
    auto carve = [&](size_t bytes) { void* r = (void*)p; p += (bytes + 255) & ~(size_t)255; return r; };
    unsigned short* bufA = (unsigned short*)carve((size_t)NN * 256 * 2);  // h1 / xw
    unsigned short* bufB = (unsigned short*)carve((size_t)NN * 256 * 2);  // h0 / h
    int*   cnt     = (int*)carve((size_t)NN * 4);
    float* dinv    = (float*)carve((size_t)NN * 4);
    int*   row_ptr = (int*)carve((size_t)(NN + 1) * 4);
    int*   cursor  = (int*)carve((size_t)(NN + 1) * 4);
    int*   colA    = (int*)carve((size_t)NE * 4);
    int*   gstart  = (int*)carve((size_t)(NG + 1) * 4);
    float* fp_emb  = (float*)carve((size_t)NG * 256 * 4);
    int*   bsum    = (int*)carve((size_t)NBLK * 4);
    int*   bpre    = (int*)carve((size_t)NBLK * 4);
    unsigned short* w1t  = (unsigned short*)carve((size_t)128 * 384 * 2);
    unsigned short* w2t  = (unsigned short*)carve((size_t)128 * 128 * 2);
    unsigned short* cwt[4];
    cwt[0] = (unsigned short*)carve((size_t)256 * 128 * 2);
    for (int l = 1; l < 4; ++l) cwt[l] = (unsigned short*)carve((size_t)256 * 256 * 2);
    unsigned short* fpwt = (unsigned short*)carve((size_t)256 * 2048 * 2);
    unsigned short* fpbf = (unsigned short*)carve((size_t)NG * 2048 * 2);
    unsigned short* l1wt = (unsigned short*)carve((size_t)128 * 512 * 2);
    unsigned short* zcat = (unsigned short*)carve((size_t)NG * 512 * 2);
    float* z1      = (float*)carve((size_t)NG * 128 * 4);

    // --- CSR build (parallel scan) ---
    hipMemsetAsync(cnt, 0, (size_t)NN * 4, stream);
    k_count<<<(NE + 255) / 256, 256, 0, stream>>>(dst, cnt);
    k_dinv<<<(NN + 255) / 256, 256, 0, stream>>>(cnt, dinv);
    k_bsum<<<NBLK, 256, 0, stream>>>(cnt, bsum);
    k_bscan<<<1, 512, 0, stream>>>(bsum, bpre);
    k_rowptr<<<NBLK, 256, 0, stream>>>(cnt, bpre, row_ptr, cursor);
    k_fill<<<(NE + 255) / 256, 256, 0, stream>>>(src, dst, cursor, colA);

    // --- weight transpose-converts (f32 [K][N] -> bf16 [N][K]) ---
    k_t<<<(49152 + 255) / 256, 256, 0, stream>>>(proj_w1, w1t, 49152, 7);
    k_t<<<(16384 + 255) / 256, 256, 0, stream>>>(proj_w2, w2t, 16384, 7);
    k_t<<<(32768 + 255) / 256, 256, 0, stream>>>(conv_w[0], cwt[0], 32768, 8);
    for (int l = 1; l < 4; ++l)
        k_t<<<(65536 + 255) / 256, 256, 0, stream>>>(conv_w[l], cwt[l], 65536, 8);
    k_t<<<(524288 + 255) / 256, 256, 0, stream>>>(fp_w, fpwt, 524288, 8);
    k_t<<<(65536 + 255) / 256, 256, 0, stream>>>(lin1_w, l1wt, 65536, 7);
    k_cvt<<<(NG * 2048 / 8 + 255) / 256, 256, 0, stream>>>(fingerprint, fpbf, NG * 2048 / 8);

    // --- fingerprint linear, split-K=4: fp_emb = bias; += fpbf @ fp_w chunks ---
    k_binit<<<NG, 256, 0, stream>>>(fp_emb, fp_b);
    k_mmA<false, false, false, true><<<dim3((NG + 127) / 128, 2, 4), 256, 0, stream>>>(
        fpbf, fpwt, fp_emb, nullptr, NG, 256, 2048, 512);
    k_z<<<NG, 256, 0, stream>>>(fp_emb, zcat);

    const int mg = (NN + 127) / 128;  // 782

    // --- projector: h1 = relu(gather @ w1 + b1) -> bufA [NN,128] bf16 ---
    k_mm<true, true, true, true><<<dim3(mg, 1), 256, 0, stream>>>(
        nullptr, w1t, bufA, proj_b1, NN, 128, 384,
        atom_idx, degree_idx, charge_idx, emb_atom, emb_degree, emb_charge);
    // --- h0 = h1 @ w2 + b2 -> bufB [NN,128] bf16 ---
    k_mmA<true, false, true, false><<<dim3(mg, 1), 256, 0, stream>>>(
        bufA, w2t, bufB, proj_b2, NN, 128, 128, 0);

    // --- layer 0 reordered: S*(h@W) = (S*h)@W — aggregate on 128-wide h0 first ---
    k_scat<128, false><<<NN / 4, 256, 0, stream>>>(bufB, bufA, dinv, row_ptr, colA, nullptr);
    k_mmA<true, true, true, false><<<dim3(mg, 2), 256, 0, stream>>>(
        bufA, cwt[0], bufB, conv_b[0], NN, 256, 128, 0);

    // --- layers 1-3: GEMM then aggregate (+bias+relu fused) ---
    for (int l = 1; l < 4; ++l) {
        k_mmA<false, false, true, false><<<dim3(mg, 2), 256, 0, stream>>>(
            bufB, cwt[l], bufA, nullptr, NN, 256, 256, 0);
        k_scat256<<<NN / 2, 256, 0, stream>>>(bufA, bufB, dinv, row_ptr, colA, conv_b[l]);
    }

    // --- pooling (bf16 into zcat cols 256..511) ---
    k_bounds<<<(NN + 255) / 256, 256, 0, stream>>>(batch, gstart);
    k_pool<<<NG, 64, 0, stream>>>(bufB, gstart, zcat);

    // --- head: z1 = relu(zcat @ lin1 + b1) (f32), out = z1 . w2 + b2 ---
    k_mmA<true, true, false, false><<<dim3((NG + 127) / 128, 1), 256, 0, stream>>>(
        zcat, l1wt, z1, lin1_b, NG, 128, 512, 0);
    k_dot<<<NG / 4, 256, 0, stream>>>(z1, lin2_w, lin2_b, out);
}

// Round 6
// 789.826 us; speedup vs baseline: 1.0201x; 1.0201x over previous
//
#include <hip/hip_runtime.h>
#include <stdint.h>

#define NN 100000   // nodes
#define NE 800000   // edges
#define NG 4000     // graphs
#define NBLK ((NN + 255) / 256)   // 391 scan blocks

typedef __attribute__((ext_vector_type(8))) short s16x8;   // 8 bf16 (4 VGPRs)
typedef __attribute__((ext_vector_type(4))) float f32x4;
typedef __attribute__((ext_vector_type(2))) float f32x2;

__device__ __forceinline__ float b2f(unsigned short u) {
    return __uint_as_float(((unsigned int)u) << 16);
}
__device__ __forceinline__ unsigned short f2b(float f) {
    unsigned int x = __float_as_uint(f);
    x = x + 0x7FFFu + ((x >> 16) & 1u);   // RNE
    return (unsigned short)(x >> 16);
}
__device__ __forceinline__ s16x8 cvt8(const float* __restrict__ p) {
    float4 a = *(const float4*)p;
    float4 b = *(const float4*)(p + 4);
    s16x8 r = {(short)f2b(a.x), (short)f2b(a.y), (short)f2b(a.z), (short)f2b(a.w),
               (short)f2b(b.x), (short)f2b(b.y), (short)f2b(b.z), (short)f2b(b.w)};
    return r;
}

// async global->LDS, 16B per lane. LDS dest = wave-uniform base + lane*16.
__device__ __forceinline__ void gload16(const void* g, void* l) {
    __builtin_amdgcn_global_load_lds((const __attribute__((address_space(1))) unsigned int*)g,
                                     (__attribute__((address_space(3))) unsigned int*)l, 16, 0, 0);
}

// accumulate 8 bf16 into 4 f32 pairs via v_pk_add_f32 (2 adds/inst)
__device__ __forceinline__ void acc8(f32x2* acc, s16x8 r) {
    const unsigned int* u = (const unsigned int*)&r;
#pragma unroll
    for (int q = 0; q < 4; ++q) {
        unsigned int w = u[q];
        f32x2 x;
        x[0] = __uint_as_float(w << 16);          // even col (low bf16)
        x[1] = __uint_as_float(w & 0xFFFF0000u);  // odd col (high bf16)
        asm("v_pk_add_f32 %0, %1, %0" : "+v"(acc[q]) : "v"(x));
    }
}

// ---------------- degree / CSR build ----------------
__global__ void k_count(const int* __restrict__ dst, int* __restrict__ cnt) {
    int e = blockIdx.x * 256 + threadIdx.x;
    if (e < NE) atomicAdd(&cnt[dst[e]], 1);
}

__global__ void k_dinv(const int* __restrict__ cnt, float* __restrict__ dinv) {
    int n = blockIdx.x * 256 + threadIdx.x;
    if (n < NN) dinv[n] = rsqrtf((float)(cnt[n] + 1));  // +1 self loop
}

__global__ __launch_bounds__(256) void k_bsum(const int* __restrict__ cnt, int* __restrict__ bsum) {
    __shared__ int s[256];
    int i = blockIdx.x * 256 + threadIdx.x;
    s[threadIdx.x] = (i < NN) ? cnt[i] : 0;
    __syncthreads();
    for (int off = 128; off; off >>= 1) {
        if (threadIdx.x < off) s[threadIdx.x] += s[threadIdx.x + off];
        __syncthreads();
    }
    if (threadIdx.x == 0) bsum[blockIdx.x] = s[0];
}

__global__ __launch_bounds__(512) void k_bscan(const int* __restrict__ bsum, int* __restrict__ bpre) {
    __shared__ int s[512];
    int t = threadIdx.x;
    int v = (t < NBLK) ? bsum[t] : 0;
    s[t] = v;
    __syncthreads();
    for (int off = 1; off < 512; off <<= 1) {
        int u = (t >= off) ? s[t - off] : 0;
        __syncthreads();
        s[t] += u;
        __syncthreads();
    }
    if (t < NBLK) bpre[t] = s[t] - v;   // exclusive prefix of block sums
}

__global__ __launch_bounds__(256) void k_rowptr(const int* __restrict__ cnt, const int* __restrict__ bpre,
                                                int* __restrict__ row_ptr, int* __restrict__ cursor) {
    __shared__ int s[256];
    int t = threadIdx.x;
    int i = blockIdx.x * 256 + t;
    int v = (i < NN) ? cnt[i] : 0;
    s[t] = v;
    __syncthreads();
    for (int off = 1; off < 256; off <<= 1) {
        int u = (t >= off) ? s[t - off] : 0;
        __syncthreads();
        s[t] += u;
        __syncthreads();
    }
    if (i < NN) {
        int excl = bpre[blockIdx.x] + s[t] - v;
        row_ptr[i] = excl;
        cursor[i] = excl;
        if (i == NN - 1) row_ptr[NN] = NE;
    }
}

__global__ void k_fill(const int* __restrict__ src, const int* __restrict__ dst,
                       int* __restrict__ cursor, int* __restrict__ colA) {
    int e = blockIdx.x * 256 + threadIdx.x;
    if (e < NE) {
        int d = dst[e];
        int p = atomicAdd(&cursor[d], 1);
        colA[p] = src[e];
    }
}

// ---------------- weight transpose-convert: src f32 [K][N] -> dst bf16 [N][K] ----------------
__global__ void k_t(const float* __restrict__ src, unsigned short* __restrict__ dst, int KN, int ln) {
    int i = blockIdx.x * 256 + threadIdx.x;
    if (i < KN) {
        int k = i >> ln, n = i & ((1 << ln) - 1);
        dst[(size_t)n * (KN >> ln) + k] = f2b(src[i]);
    }
}

// fingerprint f32 -> bf16 (no transpose), 8 elems/thread
__global__ void k_cvt(const float* __restrict__ src, unsigned short* __restrict__ dst, int n8) {
    int i = blockIdx.x * 256 + threadIdx.x;
    if (i < n8) *(s16x8*)&dst[(size_t)i * 8] = cvt8(&src[(size_t)i * 8]);
}

// init fp_emb with bias (split-K GEMM accumulates on top)
__global__ void k_binit(float* __restrict__ fe, const float* __restrict__ b) {
    int i = blockIdx.x * 256 + threadIdx.x;   // NG*256 threads
    fe[i] = b[i & 255];
}

// fp_emb f32 -> zcat bf16 (cols 0..255 of [NG][512])
__global__ void k_z(const float* __restrict__ fe, unsigned short* __restrict__ zcat) {
    int i = blockIdx.x * 256 + threadIdx.x;   // NG*256 threads
    int g = i >> 8, c = i & 255;
    zcat[(size_t)g * 512 + c] = f2b(fe[i]);
}

// ---------------- reg-staged MFMA GEMM with embedding gather (projector layer 1) ----------------
template <bool GATHER, bool BIAS, bool RELU, bool CBF16>
__global__ __launch_bounds__(256) void k_mm(
    const unsigned short* __restrict__ A, const unsigned short* __restrict__ Bt,
    void* __restrict__ Cv, const float* __restrict__ bias, int M, int N, int K,
    const int* __restrict__ ai, const int* __restrict__ di, const int* __restrict__ ci,
    const float* __restrict__ ea, const float* __restrict__ ed, const float* __restrict__ ec) {
    __shared__ unsigned short As[128 * 40];   // stride 40 shorts: 2-way bank alias = free
    __shared__ unsigned short Bs[128 * 40];
    const int tid = threadIdx.x;
    const int row0 = blockIdx.x * 128, col0 = blockIdx.y * 128;
    const int lane = tid & 63, wid = tid >> 6;
    const int wrow = (wid >> 1) * 64, wcol = (wid & 1) * 64;
    const int lr = lane & 15, lk8 = (lane >> 4) * 8;

    const int sr = tid >> 1;          // staging row 0..127
    const int skc = (tid & 1) * 16;   // staging k offset {0,16}
    const int agrow = row0 + sr;
    const int bgrow = col0 + sr;
    int ia = 0, idg = 0, ic = 0;
    if (GATHER && agrow < M) { ia = ai[agrow] * 128; idg = di[agrow] * 128; ic = ci[agrow] * 128; }

    f32x4 acc[4][4] = {};

    for (int kb = 0; kb < K; kb += 32) {
        if (kb) __syncthreads();
#pragma unroll
        for (int c = 0; c < 2; ++c) {
            int kloc = skc + c * 8;
            s16x8 v = {};
            if (agrow < M) {
                if (GATHER) {
                    int kg = kb + kloc;
                    const float* p = (kg < 128) ? (ea + ia + kg)
                                   : (kg < 256) ? (ed + idg + kg - 128)
                                                : (ec + ic + kg - 256);
                    v = cvt8(p);
                } else {
                    v = *(const s16x8*)&A[(size_t)agrow * K + kb + kloc];
                }
            }
            *(s16x8*)&As[sr * 40 + kloc] = v;
            s16x8 w = *(const s16x8*)&Bt[(size_t)bgrow * K + kb + kloc];
            *(s16x8*)&Bs[sr * 40 + kloc] = w;
        }
        __syncthreads();
        s16x8 af[4], bfr[4];
#pragma unroll
        for (int f = 0; f < 4; ++f)
            af[f] = *(const s16x8*)&As[(wrow + f * 16 + lr) * 40 + lk8];
#pragma unroll
        for (int f = 0; f < 4; ++f)
            bfr[f] = *(const s16x8*)&Bs[(wcol + f * 16 + lr) * 40 + lk8];
#pragma unroll
        for (int fm = 0; fm < 4; ++fm)
#pragma unroll
            for (int fn = 0; fn < 4; ++fn)
                acc[fm][fn] = __builtin_amdgcn_mfma_f32_16x16x32_bf16(af[fm], bfr[fn], acc[fm][fn], 0, 0, 0);
    }
#pragma unroll
    for (int fm = 0; fm < 4; ++fm) {
#pragma unroll
        for (int r = 0; r < 4; ++r) {
            int row = row0 + wrow + fm * 16 + (lane >> 4) * 4 + r;
            if (row < M) {
#pragma unroll
                for (int fn = 0; fn < 4; ++fn) {
                    int col = col0 + wcol + fn * 16 + lr;
                    float v = acc[fm][fn][r];
                    if (BIAS) v += bias[col];
                    if (RELU) v = fmaxf(v, 0.f);
                    if (CBF16) ((unsigned short*)Cv)[(size_t)row * N + col] = f2b(v);
                    else       ((float*)Cv)[(size_t)row * N + col] = v;
                }
            }
        }
    }
}

// ---------------- m97-style MFMA GEMM: global_load_lds staging, linear LDS [128][32] ----------------
// A bf16 [M][K] row-major, Bt bf16 [N][K] row-major (K%32==0, N%128==0).
// SPLITK: blockIdx.z selects K-chunk of size kc; f32 atomicAdd epilogue (no bias/relu).
// PRES: multiply output row by pres[row] (dinv prescale for GCN aggregation).
template <bool BIAS, bool RELU, bool CBF16, bool SPLITK, bool PRES>
__global__ __launch_bounds__(256) void k_mmA(
    const unsigned short* __restrict__ A, const unsigned short* __restrict__ Bt,
    void* __restrict__ Cv, const float* __restrict__ bias, const float* __restrict__ pres,
    int M, int N, int K, int kc) {
    __shared__ unsigned short As[128 * 32];
    __shared__ unsigned short Bs[128 * 32];
    const int tid = threadIdx.x;
    const int row0 = blockIdx.x * 128, col0 = blockIdx.y * 128;
    const int lane = tid & 63, wid = tid >> 6;
    const int wrow = (wid >> 1) * 64, wcol = (wid & 1) * 64;
    const int lr = lane & 15, lk8 = (lane >> 4) * 8;

    const int k0 = SPLITK ? blockIdx.z * kc : 0;
    const int k1 = SPLITK ? k0 + kc : K;

    const int sra = wid * 32 + (lane >> 2);
    const int sca = (lane & 3) * 8;
    const unsigned short* a0 = A + (size_t)min(row0 + sra, M - 1) * K + sca;
    const unsigned short* a1 = A + (size_t)min(row0 + sra + 16, M - 1) * K + sca;
    const unsigned short* b0 = Bt + (size_t)(col0 + sra) * K + sca;
    const unsigned short* b1 = Bt + (size_t)(col0 + sra + 16) * K + sca;
    unsigned short* lA0 = &As[(wid * 2 + 0) * 512];
    unsigned short* lA1 = &As[(wid * 2 + 1) * 512];
    unsigned short* lB0 = &Bs[(wid * 2 + 0) * 512];
    unsigned short* lB1 = &Bs[(wid * 2 + 1) * 512];

    f32x4 acc[4][4] = {};

    for (int kb = k0; kb < k1; kb += 32) {
        if (kb != k0) __syncthreads();
        gload16(a0 + kb, lA0);
        gload16(a1 + kb, lA1);
        gload16(b0 + kb, lB0);
        gload16(b1 + kb, lB1);
        __syncthreads();   // compiler drains vmcnt before s_barrier
        s16x8 af[4], bfr[4];
#pragma unroll
        for (int f = 0; f < 4; ++f)
            af[f] = *(const s16x8*)&As[(wrow + f * 16 + lr) * 32 + lk8];
#pragma unroll
        for (int f = 0; f < 4; ++f)
            bfr[f] = *(const s16x8*)&Bs[(wcol + f * 16 + lr) * 32 + lk8];
#pragma unroll
        for (int fm = 0; fm < 4; ++fm)
#pragma unroll
            for (int fn = 0; fn < 4; ++fn)
                acc[fm][fn] = __builtin_amdgcn_mfma_f32_16x16x32_bf16(af[fm], bfr[fn], acc[fm][fn], 0, 0, 0);
    }
#pragma unroll
    for (int fm = 0; fm < 4; ++fm) {
#pragma unroll
        for (int r = 0; r < 4; ++r) {
            int row = row0 + wrow + fm * 16 + (lane >> 4) * 4 + r;
            if (row < M) {
                float pr = PRES ? pres[row] : 1.f;
#pragma unroll
                for (int fn = 0; fn < 4; ++fn) {
                    int col = col0 + wcol + fn * 16 + lr;
                    float v = acc[fm][fn][r];
                    if (SPLITK) {
                        atomicAdd(&((float*)Cv)[(size_t)row * N + col], v);
                    } else {
                        if (BIAS) v += bias[col];
                        if (RELU) v = fmaxf(v, 0.f);
                        if (PRES) v *= pr;
                        if (CBF16) ((unsigned short*)Cv)[(size_t)row * N + col] = f2b(v);
                        else       ((float*)Cv)[(size_t)row * N + col] = v;
                    }
                }
            }
        }
    }
}

// ---------------- GCN aggregate on dinv-PRESCALED rows ----------------
// WPN waves per node (W = WPN*128). 4 groups of 16 lanes; group g takes edges
// beg+g, stride 4, unroll 2 -> 8 row-gathers in flight per wave. Inner loop is
// pure bf16-sum via v_pk_add_f32. Epilogue: (sum + self) * dinv[v] (+bias,relu).
template <int WPN, bool FUSE>
__global__ __launch_bounds__(256) void k_scat2(const unsigned short* __restrict__ xw,
                                               unsigned short* __restrict__ hout,
                                               const float* __restrict__ dinv,
                                               const int* __restrict__ row_ptr,
                                               const int* __restrict__ colA,
                                               const float* __restrict__ bias) {
    constexpr int W = WPN * 128;
    const int wid = threadIdx.x >> 6, lane = threadIdx.x & 63;
    const int gw = blockIdx.x * 4 + wid;
    const int v = (WPN == 2) ? (gw >> 1) : gw;
    const int cs = (WPN == 2) ? (gw & 1) * 128 : 0;
    const int grp = lane >> 4, li = lane & 15;
    const int c0 = cs + li * 8;

    f32x2 acc[4] = {};
    const int beg = row_ptr[v], end = row_ptr[v + 1];
    int p = beg + grp;
    for (; p + 4 < end; p += 8) {
        int s0 = colA[p], s1 = colA[p + 4];
        s16x8 r0 = *(const s16x8*)&xw[(size_t)s0 * W + c0];
        s16x8 r1 = *(const s16x8*)&xw[(size_t)s1 * W + c0];
        acc8(acc, r0);
        acc8(acc, r1);
    }
    if (p < end) {
        int s0 = colA[p];
        s16x8 r0 = *(const s16x8*)&xw[(size_t)s0 * W + c0];
        acc8(acc, r0);
    }

    const float dv = dinv[v];
    s16x8 rs = *(const s16x8*)&xw[(size_t)v * W + c0];   // self (prescaled)
    unsigned short o[8];
#pragma unroll
    for (int q = 0; q < 4; ++q) {
#pragma unroll
        for (int h = 0; h < 2; ++h) {
            float a = acc[q][h];
            a += __shfl_xor(a, 16);
            a += __shfl_xor(a, 32);          // all 4 groups summed
            a += b2f((unsigned short)rs[2 * q + h]);  // self once, post-reduce
            a *= dv;
            if (FUSE) a = fmaxf(a + bias[c0 + 2 * q + h], 0.f);
            o[2 * q + h] = f2b(a);
        }
    }
    if (grp == 0) *(s16x8*)&hout[(size_t)v * W + c0] = *(const s16x8*)o;
}

// ---------------- graph boundaries from sorted batch ----------------
__global__ void k_bounds(const int* __restrict__ batch, int* __restrict__ gstart) {
    int n = blockIdx.x * 256 + threadIdx.x;
    if (n >= NN) return;
    int b = batch[n];
    if (n == 0) {
        for (int g = 0; g <= b; ++g) gstart[g] = 0;
    } else {
        int pb = batch[n - 1];
        if (pb != b)
            for (int g = pb + 1; g <= b; ++g) gstart[g] = n;
    }
    if (n == NN - 1) {
        for (int g = b + 1; g <= NG; ++g) gstart[g] = NN;
    }
}

// ---------------- pooling: bf16 sums into zcat cols 256..511 ----------------
__global__ __launch_bounds__(64) void k_pool(const unsigned short* __restrict__ h,
                                             const int* __restrict__ gstart,
                                             unsigned short* __restrict__ zcat) {
    int g = blockIdx.x;
    int lane = threadIdx.x;
    int c0 = lane * 4;
    int beg = gstart[g], end = gstart[g + 1];
    float a0 = 0.f, a1 = 0.f, a2 = 0.f, a3 = 0.f;
    for (int n = beg; n < end; ++n) {
        ushort4 r = *(const ushort4*)&h[(size_t)n * 256 + c0];
        a0 += b2f(r.x); a1 += b2f(r.y); a2 += b2f(r.z); a3 += b2f(r.w);
    }
    ushort4 o;
    o.x = f2b(a0); o.y = f2b(a1); o.z = f2b(a2); o.w = f2b(a3);
    *(ushort4*)&zcat[(size_t)g * 512 + 256 + c0] = o;
}

// ---------------- final dot: out[g] = z1[g] . w2 + b2 ----------------
__global__ __launch_bounds__(256) void k_dot(const float* __restrict__ z1,
                                             const float* __restrict__ w2,
                                             const float* __restrict__ b2,
                                             float* __restrict__ out) {
    int wid = threadIdx.x >> 6, lane = threadIdx.x & 63;
    int g = blockIdx.x * 4 + wid;   // NG % 4 == 0
    float s = z1[(size_t)g * 128 + lane] * w2[lane]
            + z1[(size_t)g * 128 + 64 + lane] * w2[64 + lane];
#pragma unroll
    for (int off = 32; off; off >>= 1) s += __shfl_xor(s, off);
    if (lane == 0) out[g] = s + b2[0];
}

// ---------------- launch ----------------
extern "C" void kernel_launch(void* const* d_in, const int* in_sizes, int n_in,
                              void* d_out, int out_size, void* d_ws, size_t ws_size,
                              hipStream_t stream) {
    const int* atom_idx   = (const int*)d_in[0];
    const int* degree_idx = (const int*)d_in[1];
    const int* charge_idx = (const int*)d_in[2];
    const int* edge_index = (const int*)d_in[3];
    const int* batch      = (const int*)d_in[4];
    const float* fingerprint = (const float*)d_in[5];
    const float* emb_atom   = (const float*)d_in[6];
    const float* emb_degree = (const float*)d_in[7];
    const float* emb_charge = (const float*)d_in[8];
    const float* proj_w1 = (const float*)d_in[9];
    const float* proj_b1 = (const float*)d_in[10];
    const float* proj_w2 = (const float*)d_in[11];
    const float* proj_b2 = (const float*)d_in[12];
    const float* fp_w = (const float*)d_in[13];
    const float* fp_b = (const float*)d_in[14];
    const float* conv_w[4] = {(const float*)d_in[15], (const float*)d_in[17],
                              (const float*)d_in[19], (const float*)d_in[21]};
    const float* conv_b[4] = {(const float*)d_in[16], (const float*)d_in[18],
                              (const float*)d_in[20], (const float*)d_in[22]};
    const float* lin1_w = (const float*)d_in[23];
    const float* lin1_b = (const float*)d_in[24];
    const float* lin2_w = (const float*)d_in[25];
    const float* lin2_b = (const float*)d_in[26];
    float* out = (float*)d_out;

    const int* src = edge_index;
    const int* dst = edge_index + NE;

    // workspace carve (256B aligned)
    char* p = (char*)d_ws;
    auto carve = [&](size_t bytes) { void* r = (void*)p; p += (bytes + 255) & ~(size_t)255; return r; };
    unsigned short* bufA = (unsigned short*)carve((size_t)NN * 256 * 2);
    unsigned short* bufB = (unsigned short*)carve((size_t)NN * 256 * 2);
    int*   cnt     = (int*)carve((size_t)NN * 4);
    float* dinv    = (float*)carve((size_t)NN * 4);
    int*   row_ptr = (int*)carve((size_t)(NN + 1) * 4);
    int*   cursor  = (int*)carve((size_t)(NN + 1) * 4);
    int*   colA    = (int*)carve((size_t)NE * 4);
    int*   gstart  = (int*)carve((size_t)(NG + 1) * 4);
    float* fp_emb  = (float*)carve((size_t)NG * 256 * 4);
    int*   bsum    = (int*)carve((size_t)NBLK * 4);
    int*   bpre    = (int*)carve((size_t)NBLK * 4);
    unsigned short* w1t  = (unsigned short*)carve((size_t)128 * 384 * 2);
    unsigned short* w2t  = (unsigned short*)carve((size_t)128 * 128 * 2);
    unsigned short* cwt[4];
    cwt[0] = (unsigned short*)carve((size_t)256 * 128 * 2);
    for (int l = 1; l < 4; ++l) cwt[l] = (unsigned short*)carve((size_t)256 * 256 * 2);
    unsigned short* fpwt = (unsigned short*)carve((size_t)256 * 2048 * 2);
    unsigned short* fpbf = (unsigned short*)carve((size_t)NG * 2048 * 2);
    unsigned short* l1wt = (unsigned short*)carve((size_t)128 * 512 * 2);
    unsigned short* zcat = (unsigned short*)carve((size_t)NG * 512 * 2);
    float* z1      = (float*)carve((size_t)NG * 128 * 4);

    // --- CSR build (parallel scan) ---
    hipMemsetAsync(cnt, 0, (size_t)NN * 4, stream);
    k_count<<<(NE + 255) / 256, 256, 0, stream>>>(dst, cnt);
    k_dinv<<<(NN + 255) / 256, 256, 0, stream>>>(cnt, dinv);
    k_bsum<<<NBLK, 256, 0, stream>>>(cnt, bsum);
    k_bscan<<<1, 512, 0, stream>>>(bsum, bpre);
    k_rowptr<<<NBLK, 256, 0, stream>>>(cnt, bpre, row_ptr, cursor);
    k_fill<<<(NE + 255) / 256, 256, 0, stream>>>(src, dst, cursor, colA);

    // --- weight transpose-converts (f32 [K][N] -> bf16 [N][K]) ---
    k_t<<<(49152 + 255) / 256, 256, 0, stream>>>(proj_w1, w1t, 49152, 7);
    k_t<<<(16384 + 255) / 256, 256, 0, stream>>>(proj_w2, w2t, 16384, 7);
    k_t<<<(32768 + 255) / 256, 256, 0, stream>>>(conv_w[0], cwt[0], 32768, 8);
    for (int l = 1; l < 4; ++l)
        k_t<<<(65536 + 255) / 256, 256, 0, stream>>>(conv_w[l], cwt[l], 65536, 8);
    k_t<<<(524288 + 255) / 256, 256, 0, stream>>>(fp_w, fpwt, 524288, 8);
    k_t<<<(65536 + 255) / 256, 256, 0, stream>>>(lin1_w, l1wt, 65536, 7);
    k_cvt<<<(NG * 2048 / 8 + 255) / 256, 256, 0, stream>>>(fingerprint, fpbf, NG * 2048 / 8);

    // --- fingerprint linear, split-K=4 ---
    k_binit<<<NG, 256, 0, stream>>>(fp_emb, fp_b);
    k_mmA<false, false, false, true, false><<<dim3((NG + 127) / 128, 2, 4), 256, 0, stream>>>(
        fpbf, fpwt, fp_emb, nullptr, nullptr, NG, 256, 2048, 512);
    k_z<<<NG, 256, 0, stream>>>(fp_emb, zcat);

    const int mg = (NN + 127) / 128;  // 782

    // --- projector: h1 = relu(gather @ w1 + b1) -> bufA [NN,128] bf16 ---
    k_mm<true, true, true, true><<<dim3(mg, 1), 256, 0, stream>>>(
        nullptr, w1t, bufA, proj_b1, NN, 128, 384,
        atom_idx, degree_idx, charge_idx, emb_atom, emb_degree, emb_charge);
    // --- h0' = (h1 @ w2 + b2) * dinv -> bufB [NN,128] bf16 (prescaled) ---
    k_mmA<true, false, true, false, true><<<dim3(mg, 1), 256, 0, stream>>>(
        bufA, w2t, bufB, proj_b2, dinv, NN, 128, 128, 0);

    // --- layer 0 reordered: agg = (S*h0) -> bufA; h = relu(agg@W0 + b0) -> bufB ---
    k_scat2<1, false><<<NN / 4, 256, 0, stream>>>(bufB, bufA, dinv, row_ptr, colA, nullptr);
    k_mmA<true, true, true, false, false><<<dim3(mg, 2), 256, 0, stream>>>(
        bufA, cwt[0], bufB, conv_b[0], nullptr, NN, 256, 128, 0);

    // --- layers 1-3: xw' = (h@W)*dinv -> bufA; h = relu(S-sum + b) -> bufB ---
    for (int l = 1; l < 4; ++l) {
        k_mmA<false, false, true, false, true><<<dim3(mg, 2), 256, 0, stream>>>(
            bufB, cwt[l], bufA, nullptr, dinv, NN, 256, 256, 0);
        k_scat2<2, true><<<NN / 2, 256, 0, stream>>>(bufA, bufB, dinv, row_ptr, colA, conv_b[l]);
    }

    // --- pooling (bf16 into zcat cols 256..511) ---
    k_bounds<<<(NN + 255) / 256, 256, 0, stream>>>(batch, gstart);
    k_pool<<<NG, 64, 0, stream>>>(bufB, gstart, zcat);

    // --- head: z1 = relu(zcat @ lin1 + b1) (f32), out = z1 . w2 + b2 ---
    k_mmA<true, true, false, false, false><<<dim3((NG + 127) / 128, 1), 256, 0, stream>>>(
        zcat, l1wt, z1, lin1_b, nullptr, NG, 128, 512, 0);
    k_dot<<<NG / 4, 256, 0, stream>>>(z1, lin2_w, lin2_b, out);
}

// Round 8
// 749.055 us; speedup vs baseline: 1.0757x; 1.0544x over previous
//
#include <hip/hip_runtime.h>
#include <stdint.h>

#define NN 100000   // nodes
#define NE 800000   // edges
#define NG 4000     // graphs
#define NBLK ((NN + 255) / 256)   // 391 scan blocks

typedef __attribute__((ext_vector_type(8))) short s16x8;   // 8 bf16 (4 VGPRs)
typedef __attribute__((ext_vector_type(4))) float f32x4;
typedef __attribute__((ext_vector_type(2))) float f32x2;

__device__ __forceinline__ float b2f(unsigned short u) {
    return __uint_as_float(((unsigned int)u) << 16);
}
__device__ __forceinline__ unsigned short f2b(float f) {
    unsigned int x = __float_as_uint(f);
    x = x + 0x7FFFu + ((x >> 16) & 1u);   // RNE
    return (unsigned short)(x >> 16);
}
__device__ __forceinline__ s16x8 cvt8(const float* __restrict__ p) {
    float4 a = *(const float4*)p;
    float4 b = *(const float4*)(p + 4);
    s16x8 r = {(short)f2b(a.x), (short)f2b(a.y), (short)f2b(a.z), (short)f2b(a.w),
               (short)f2b(b.x), (short)f2b(b.y), (short)f2b(b.z), (short)f2b(b.w)};
    return r;
}

// async global->LDS, 16B per lane. LDS dest = wave-uniform base + lane*16.
__device__ __forceinline__ void gload16(const void* g, void* l) {
    __builtin_amdgcn_global_load_lds((const __attribute__((address_space(1))) unsigned int*)g,
                                     (__attribute__((address_space(3))) unsigned int*)l, 16, 0, 0);
}

// accumulate 8 bf16 into 4 f32 pairs via v_pk_add_f32 (2 adds/inst)
__device__ __forceinline__ void acc8(f32x2* acc, s16x8 r) {
    const unsigned int* u = (const unsigned int*)&r;
#pragma unroll
    for (int q = 0; q < 4; ++q) {
        unsigned int w = u[q];
        f32x2 x;
        x[0] = __uint_as_float(w << 16);          // even col (low bf16)
        x[1] = __uint_as_float(w & 0xFFFF0000u);  // odd col (high bf16)
        asm("v_pk_add_f32 %0, %1, %0" : "+v"(acc[q]) : "v"(x));
    }
}

// ---------------- degree / CSR build ----------------
__global__ void k_count(const int* __restrict__ dst, int* __restrict__ cnt) {
    int e = blockIdx.x * 256 + threadIdx.x;
    if (e < NE) atomicAdd(&cnt[dst[e]], 1);
}

__global__ void k_dinv(const int* __restrict__ cnt, float* __restrict__ dinv) {
    int n = blockIdx.x * 256 + threadIdx.x;
    if (n < NN) dinv[n] = rsqrtf((float)(cnt[n] + 1));  // +1 self loop
}

__global__ __launch_bounds__(256) void k_bsum(const int* __restrict__ cnt, int* __restrict__ bsum) {
    __shared__ int s[256];
    int i = blockIdx.x * 256 + threadIdx.x;
    s[threadIdx.x] = (i < NN) ? cnt[i] : 0;
    __syncthreads();
    for (int off = 128; off; off >>= 1) {
        if (threadIdx.x < off) s[threadIdx.x] += s[threadIdx.x + off];
        __syncthreads();
    }
    if (threadIdx.x == 0) bsum[blockIdx.x] = s[0];
}

__global__ __launch_bounds__(512) void k_bscan(const int* __restrict__ bsum, int* __restrict__ bpre) {
    __shared__ int s[512];
    int t = threadIdx.x;
    int v = (t < NBLK) ? bsum[t] : 0;
    s[t] = v;
    __syncthreads();
    for (int off = 1; off < 512; off <<= 1) {
        int u = (t >= off) ? s[t - off] : 0;
        __syncthreads();
        s[t] += u;
        __syncthreads();
    }
    if (t < NBLK) bpre[t] = s[t] - v;   // exclusive prefix of block sums
}

__global__ __launch_bounds__(256) void k_rowptr(const int* __restrict__ cnt, const int* __restrict__ bpre,
                                                int* __restrict__ row_ptr, int* __restrict__ cursor) {
    __shared__ int s[256];
    int t = threadIdx.x;
    int i = blockIdx.x * 256 + t;
    int v = (i < NN) ? cnt[i] : 0;
    s[t] = v;
    __syncthreads();
    for (int off = 1; off < 256; off <<= 1) {
        int u = (t >= off) ? s[t - off] : 0;
        __syncthreads();
        s[t] += u;
        __syncthreads();
    }
    if (i < NN) {
        int excl = bpre[blockIdx.x] + s[t] - v;
        row_ptr[i] = excl;
        cursor[i] = excl;
        if (i == NN - 1) row_ptr[NN] = NE;
    }
}

__global__ void k_fill(const int* __restrict__ src, const int* __restrict__ dst,
                       int* __restrict__ cursor, int* __restrict__ colA) {
    int e = blockIdx.x * 256 + threadIdx.x;
    if (e < NE) {
        int d = dst[e];
        int p = atomicAdd(&cursor[d], 1);
        colA[p] = src[e];
    }
}

// ---------------- weight transpose-convert: src f32 [K][N] -> dst bf16 [N][K] ----------------
__global__ void k_t(const float* __restrict__ src, unsigned short* __restrict__ dst, int KN, int ln) {
    int i = blockIdx.x * 256 + threadIdx.x;
    if (i < KN) {
        int k = i >> ln, n = i & ((1 << ln) - 1);
        dst[(size_t)n * (KN >> ln) + k] = f2b(src[i]);
    }
}

// fingerprint f32 -> bf16 (no transpose), 8 elems/thread
__global__ void k_cvt(const float* __restrict__ src, unsigned short* __restrict__ dst, int n8) {
    int i = blockIdx.x * 256 + threadIdx.x;
    if (i < n8) *(s16x8*)&dst[(size_t)i * 8] = cvt8(&src[(size_t)i * 8]);
}

// init fp_emb with bias (split-K GEMM accumulates on top)
__global__ void k_binit(float* __restrict__ fe, const float* __restrict__ b) {
    int i = blockIdx.x * 256 + threadIdx.x;   // NG*256 threads
    fe[i] = b[i & 255];
}

// fp_emb f32 -> zcat bf16 (cols 0..255 of [NG][512])
__global__ void k_z(const float* __restrict__ fe, unsigned short* __restrict__ zcat) {
    int i = blockIdx.x * 256 + threadIdx.x;   // NG*256 threads
    int g = i >> 8, c = i & 255;
    zcat[(size_t)g * 512 + c] = f2b(fe[i]);
}

// ---------------- reg-staged MFMA GEMM with embedding gather (projector layer 1) ----------------
template <bool GATHER, bool BIAS, bool RELU, bool CBF16>
__global__ __launch_bounds__(256) void k_mm(
    const unsigned short* __restrict__ A, const unsigned short* __restrict__ Bt,
    void* __restrict__ Cv, const float* __restrict__ bias, int M, int N, int K,
    const int* __restrict__ ai, const int* __restrict__ di, const int* __restrict__ ci,
    const float* __restrict__ ea, const float* __restrict__ ed, const float* __restrict__ ec) {
    __shared__ unsigned short As[128 * 40];   // stride 40 shorts: 2-way bank alias = free
    __shared__ unsigned short Bs[128 * 40];
    const int tid = threadIdx.x;
    const int row0 = blockIdx.x * 128, col0 = blockIdx.y * 128;
    const int lane = tid & 63, wid = tid >> 6;
    const int wrow = (wid >> 1) * 64, wcol = (wid & 1) * 64;
    const int lr = lane & 15, lk8 = (lane >> 4) * 8;

    const int sr = tid >> 1;          // staging row 0..127
    const int skc = (tid & 1) * 16;   // staging k offset {0,16}
    const int agrow = row0 + sr;
    const int bgrow = col0 + sr;
    int ia = 0, idg = 0, ic = 0;
    if (GATHER && agrow < M) { ia = ai[agrow] * 128; idg = di[agrow] * 128; ic = ci[agrow] * 128; }

    f32x4 acc[4][4] = {};

    for (int kb = 0; kb < K; kb += 32) {
        if (kb) __syncthreads();
#pragma unroll
        for (int c = 0; c < 2; ++c) {
            int kloc = skc + c * 8;
            s16x8 v = {};
            if (agrow < M) {
                if (GATHER) {
                    int kg = kb + kloc;
                    const float* p = (kg < 128) ? (ea + ia + kg)
                                   : (kg < 256) ? (ed + idg + kg - 128)
                                                : (ec + ic + kg - 256);
                    v = cvt8(p);
                } else {
                    v = *(const s16x8*)&A[(size_t)agrow * K + kb + kloc];
                }
            }
            *(s16x8*)&As[sr * 40 + kloc] = v;
            s16x8 w = *(const s16x8*)&Bt[(size_t)bgrow * K + kb + kloc];
            *(s16x8*)&Bs[sr * 40 + kloc] = w;
        }
        __syncthreads();
        s16x8 af[4], bfr[4];
#pragma unroll
        for (int f = 0; f < 4; ++f)
            af[f] = *(const s16x8*)&As[(wrow + f * 16 + lr) * 40 + lk8];
#pragma unroll
        for (int f = 0; f < 4; ++f)
            bfr[f] = *(const s16x8*)&Bs[(wcol + f * 16 + lr) * 40 + lk8];
#pragma unroll
        for (int fm = 0; fm < 4; ++fm)
#pragma unroll
            for (int fn = 0; fn < 4; ++fn)
                acc[fm][fn] = __builtin_amdgcn_mfma_f32_16x16x32_bf16(af[fm], bfr[fn], acc[fm][fn], 0, 0, 0);
    }
#pragma unroll
    for (int fm = 0; fm < 4; ++fm) {
#pragma unroll
        for (int r = 0; r < 4; ++r) {
            int row = row0 + wrow + fm * 16 + (lane >> 4) * 4 + r;
            if (row < M) {
#pragma unroll
                for (int fn = 0; fn < 4; ++fn) {
                    int col = col0 + wcol + fn * 16 + lr;
                    float v = acc[fm][fn][r];
                    if (BIAS) v += bias[col];
                    if (RELU) v = fmaxf(v, 0.f);
                    if (CBF16) ((unsigned short*)Cv)[(size_t)row * N + col] = f2b(v);
                    else       ((float*)Cv)[(size_t)row * N + col] = v;
                }
            }
        }
    }
}

// ---------------- 2-phase double-buffered MFMA GEMM (global_load_lds staging) ----------------
// A bf16 [M][K] row-major, Bt bf16 [N][K] row-major (K%32==0, N%128==0).
// Stage tile t+1 is issued BEFORE computing tile t; single barrier/K-step after MFMAs,
// so the staging latency hides under ds_read + 16 MFMAs (T3-minimum pattern).
// SPLITK: blockIdx.z selects K-chunk of size kc; f32 atomicAdd epilogue.
// PRES: multiply output row by pres[row] (dinv prescale for GCN aggregation).
template <bool BIAS, bool RELU, bool CBF16, bool SPLITK, bool PRES>
__global__ __launch_bounds__(256) void k_mmA(
    const unsigned short* __restrict__ A, const unsigned short* __restrict__ Bt,
    void* __restrict__ Cv, const float* __restrict__ bias, const float* __restrict__ pres,
    int M, int N, int K, int kc) {
    __shared__ unsigned short As[2][128 * 32];
    __shared__ unsigned short Bs[2][128 * 32];
    const int tid = threadIdx.x;
    const int row0 = blockIdx.x * 128, col0 = blockIdx.y * 128;
    const int lane = tid & 63, wid = tid >> 6;
    const int wrow = (wid >> 1) * 64, wcol = (wid & 1) * 64;
    const int lr = lane & 15, lk8 = (lane >> 4) * 8;

    const int k0 = SPLITK ? blockIdx.z * kc : 0;
    const int nt = (SPLITK ? kc : K) / 32;

    // staging: wave wid covers LDS rows [wid*32, wid*32+32) in two 1KB chunks.
    const int sra = wid * 32 + (lane >> 2);     // +0 / +16
    const int sca = (lane & 3) * 8;
    const unsigned short* a0 = A + (size_t)min(row0 + sra, M - 1) * K + sca + k0;
    const unsigned short* a1 = A + (size_t)min(row0 + sra + 16, M - 1) * K + sca + k0;
    const unsigned short* b0 = Bt + (size_t)(col0 + sra) * K + sca + k0;
    const unsigned short* b1 = Bt + (size_t)(col0 + sra + 16) * K + sca + k0;
    const int lo0 = (wid * 2 + 0) * 512;
    const int lo1 = (wid * 2 + 1) * 512;

    f32x4 acc[4][4] = {};

    // prologue: stage tile 0 -> buf 0
    gload16(a0, &As[0][lo0]);
    gload16(a1, &As[0][lo1]);
    gload16(b0, &Bs[0][lo0]);
    gload16(b1, &Bs[0][lo1]);
    __syncthreads();

    int cur = 0;
    for (int t = 0; t < nt; ++t) {
        if (t + 1 < nt) {   // issue next tile into the other buffer (stays in flight thru MFMAs)
            int kb = (t + 1) * 32;
            gload16(a0 + kb, &As[cur ^ 1][lo0]);
            gload16(a1 + kb, &As[cur ^ 1][lo1]);
            gload16(b0 + kb, &Bs[cur ^ 1][lo0]);
            gload16(b1 + kb, &Bs[cur ^ 1][lo1]);
        }
        s16x8 af[4], bfr[4];
#pragma unroll
        for (int f = 0; f < 4; ++f)
            af[f] = *(const s16x8*)&As[cur][(wrow + f * 16 + lr) * 32 + lk8];
#pragma unroll
        for (int f = 0; f < 4; ++f)
            bfr[f] = *(const s16x8*)&Bs[cur][(wcol + f * 16 + lr) * 32 + lk8];
#pragma unroll
        for (int fm = 0; fm < 4; ++fm)
#pragma unroll
            for (int fn = 0; fn < 4; ++fn)
                acc[fm][fn] = __builtin_amdgcn_mfma_f32_16x16x32_bf16(af[fm], bfr[fn], acc[fm][fn], 0, 0, 0);
        __syncthreads();   // drains vmcnt (tile t+1 landed) + all waves done with buf cur
        cur ^= 1;
    }
#pragma unroll
    for (int fm = 0; fm < 4; ++fm) {
#pragma unroll
        for (int r = 0; r < 4; ++r) {
            int row = row0 + wrow + fm * 16 + (lane >> 4) * 4 + r;
            if (row < M) {
                float pr = PRES ? pres[row] : 1.f;
#pragma unroll
                for (int fn = 0; fn < 4; ++fn) {
                    int col = col0 + wcol + fn * 16 + lr;
                    float v = acc[fm][fn][r];
                    if (SPLITK) {
                        atomicAdd(&((float*)Cv)[(size_t)row * N + col], v);
                    } else {
                        if (BIAS) v += bias[col];
                        if (RELU) v = fmaxf(v, 0.f);
                        if (PRES) v *= pr;
                        if (CBF16) ((unsigned short*)Cv)[(size_t)row * N + col] = f2b(v);
                        else       ((float*)Cv)[(size_t)row * N + col] = v;
                    }
                }
            }
        }
    }
}

// ---------------- GCN aggregate on dinv-PRESCALED rows, group-per-node ----------------
// 16-lane group = one (node, 128-col slice). W=128: 4 nodes/wave; W=256: 2 nodes/wave
// (2 slices each). Each group serially walks its node's edge list (unroll 2, consecutive
// colA): wave sustains 8 independent row-gathers in flight, no cross-group reduction.
// Epilogue: (sum + self) * dinv[v] (+bias, relu).
template <int WPN, bool FUSE>
__global__ __launch_bounds__(256) void k_scat3(const unsigned short* __restrict__ xw,
                                               unsigned short* __restrict__ hout,
                                               const float* __restrict__ dinv,
                                               const int* __restrict__ row_ptr,
                                               const int* __restrict__ colA,
                                               const float* __restrict__ bias) {
    constexpr int W = WPN * 128;     // feature width
    constexpr int NPW = 4 / WPN;     // nodes per wave
    const int wid = threadIdx.x >> 6, lane = threadIdx.x & 63;
    const int grp = lane >> 4, li = lane & 15;
    const int v = (blockIdx.x * 4 + wid) * NPW + grp / WPN;   // NN % (4*NPW) == 0
    const int cs = (WPN == 2) ? (grp & 1) * 128 : 0;
    const int c0 = cs + li * 8;

    f32x2 acc[4] = {};
    const int beg = row_ptr[v], end = row_ptr[v + 1];
    int p = beg;
    for (; p + 1 < end; p += 2) {
        int s0 = colA[p], s1 = colA[p + 1];
        s16x8 r0 = *(const s16x8*)&xw[(size_t)s0 * W + c0];
        s16x8 r1 = *(const s16x8*)&xw[(size_t)s1 * W + c0];
        acc8(acc, r0);
        acc8(acc, r1);
    }
    if (p < end) {
        s16x8 r0 = *(const s16x8*)&xw[(size_t)colA[p] * W + c0];
        acc8(acc, r0);
    }

    const float dv = dinv[v];
    s16x8 rs = *(const s16x8*)&xw[(size_t)v * W + c0];   // self (prescaled)
    unsigned short o[8];
#pragma unroll
    for (int j = 0; j < 8; ++j) {
        float a = acc[j >> 1][j & 1];
        a += b2f((unsigned short)rs[j]);
        a *= dv;
        if (FUSE) a = fmaxf(a + bias[c0 + j], 0.f);
        o[j] = f2b(a);
    }
    *(s16x8*)&hout[(size_t)v * W + c0] = *(const s16x8*)o;
}

// ---------------- graph boundaries from sorted batch ----------------
__global__ void k_bounds(const int* __restrict__ batch, int* __restrict__ gstart) {
    int n = blockIdx.x * 256 + threadIdx.x;
    if (n >= NN) return;
    int b = batch[n];
    if (n == 0) {
        for (int g = 0; g <= b; ++g) gstart[g] = 0;
    } else {
        int pb = batch[n - 1];
        if (pb != b)
            for (int g = pb + 1; g <= b; ++g) gstart[g] = n;
    }
    if (n == NN - 1) {
        for (int g = b + 1; g <= NG; ++g) gstart[g] = NN;
    }
}

// ---------------- pooling: bf16 sums into zcat cols 256..511 ----------------
__global__ __launch_bounds__(64) void k_pool(const unsigned short* __restrict__ h,
                                             const int* __restrict__ gstart,
                                             unsigned short* __restrict__ zcat) {
    int g = blockIdx.x;
    int lane = threadIdx.x;
    int c0 = lane * 4;
    int beg = gstart[g], end = gstart[g + 1];
    float a0 = 0.f, a1 = 0.f, a2 = 0.f, a3 = 0.f;
    for (int n = beg; n < end; ++n) {
        ushort4 r = *(const ushort4*)&h[(size_t)n * 256 + c0];
        a0 += b2f(r.x); a1 += b2f(r.y); a2 += b2f(r.z); a3 += b2f(r.w);
    }
    ushort4 o;
    o.x = f2b(a0); o.y = f2b(a1); o.z = f2b(a2); o.w = f2b(a3);
    *(ushort4*)&zcat[(size_t)g * 512 + 256 + c0] = o;
}

// ---------------- final dot: out[g] = z1[g] . w2 + b2 ----------------
__global__ __launch_bounds__(256) void k_dot(const float* __restrict__ z1,
                                             const float* __restrict__ w2,
                                             const float* __restrict__ b2,
                                             float* __restrict__ out) {
    int wid = threadIdx.x >> 6, lane = threadIdx.x & 63;
    int g = blockIdx.x * 4 + wid;   // NG % 4 == 0
    float s = z1[(size_t)g * 128 + lane] * w2[lane]
            + z1[(size_t)g * 128 + 64 + lane] * w2[64 + lane];
#pragma unroll
    for (int off = 32; off; off >>= 1) s += __shfl_xor(s, off);
    if (lane == 0) out[g] = s + b2[0];
}

// ---------------- launch ----------------
extern "C" void kernel_launch(void* const* d_in, const int* in_sizes, int n_in,
                              void* d_out, int out_size, void* d_ws, size_t ws_size,
                              hipStream_t stream) {
    const int* atom_idx   = (const int*)d_in[0];
    const int* degree_idx = (const int*)d_in[1];
    const int* charge_idx = (const int*)d_in[2];
    const int* edge_index = (const int*)d_in[3];
    const int* batch      = (const int*)d_in[4];
    const float* fingerprint = (const float*)d_in[5];
    const float* emb_atom   = (const float*)d_in[6];
    const float* emb_degree = (const float*)d_in[7];
    const float* emb_charge = (const float*)d_in[8];
    const float* proj_w1 = (const float*)d_in[9];
    const float* proj_b1 = (const float*)d_in[10];
    const float* proj_w2 = (const float*)d_in[11];
    const float* proj_b2 = (const float*)d_in[12];
    const float* fp_w = (const float*)d_in[13];
    const float* fp_b = (const float*)d_in[14];
    const float* conv_w[4] = {(const float*)d_in[15], (const float*)d_in[17],
                              (const float*)d_in[19], (const float*)d_in[21]};
    const float* conv_b[4] = {(const float*)d_in[16], (const float*)d_in[18],
                              (const float*)d_in[20], (const float*)d_in[22]};
    const float* lin1_w = (const float*)d_in[23];
    const float* lin1_b = (const float*)d_in[24];
    const float* lin2_w = (const float*)d_in[25];
    const float* lin2_b = (const float*)d_in[26];
    float* out = (float*)d_out;

    const int* src = edge_index;
    const int* dst = edge_index + NE;

    // workspace carve (256B aligned)
    char* p = (char*)d_ws;
    auto carve = [&](size_t bytes) { void* r = (void*)p; p += (bytes + 255) & ~(size_t)255; return r; };
    unsigned short* bufA = (unsigned short*)carve((size_t)NN * 256 * 2);
    unsigned short* bufB = (unsigned short*)carve((size_t)NN * 256 * 2);
    int*   cnt     = (int*)carve((size_t)NN * 4);
    float* dinv    = (float*)carve((size_t)NN * 4);
    int*   row_ptr = (int*)carve((size_t)(NN + 1) * 4);
    int*   cursor  = (int*)carve((size_t)(NN + 1) * 4);
    int*   colA    = (int*)carve((size_t)NE * 4);
    int*   gstart  = (int*)carve((size_t)(NG + 1) * 4);
    float* fp_emb  = (float*)carve((size_t)NG * 256 * 4);
    int*   bsum    = (int*)carve((size_t)NBLK * 4);
    int*   bpre    = (int*)carve((size_t)NBLK * 4);
    unsigned short* w1t  = (unsigned short*)carve((size_t)128 * 384 * 2);
    unsigned short* w2t  = (unsigned short*)carve((size_t)128 * 128 * 2);
    unsigned short* cwt[4];
    cwt[0] = (unsigned short*)carve((size_t)256 * 128 * 2);
    for (int l = 1; l < 4; ++l) cwt[l] = (unsigned short*)carve((size_t)256 * 256 * 2);
    unsigned short* fpwt = (unsigned short*)carve((size_t)256 * 2048 * 2);
    unsigned short* fpbf = (unsigned short*)carve((size_t)NG * 2048 * 2);
    unsigned short* l1wt = (unsigned short*)carve((size_t)128 * 512 * 2);
    unsigned short* zcat = (unsigned short*)carve((size_t)NG * 512 * 2);
    float* z1      = (float*)carve((size_t)NG * 128 * 4);

    // --- CSR build (parallel scan) ---
    hipMemsetAsync(cnt, 0, (size_t)NN * 4, stream);
    k_count<<<(NE + 255) / 256, 256, 0, stream>>>(dst, cnt);
    k_dinv<<<(NN + 255) / 256, 256, 0, stream>>>(cnt, dinv);
    k_bsum<<<NBLK, 256, 0, stream>>>(cnt, bsum);
    k_bscan<<<1, 512, 0, stream>>>(bsum, bpre);
    k_rowptr<<<NBLK, 256, 0, stream>>>(cnt, bpre, row_ptr, cursor);
    k_fill<<<(NE + 255) / 256, 256, 0, stream>>>(src, dst, cursor, colA);

    // --- weight transpose-converts (f32 [K][N] -> bf16 [N][K]) ---
    k_t<<<(49152 + 255) / 256, 256, 0, stream>>>(proj_w1, w1t, 49152, 7);
    k_t<<<(16384 + 255) / 256, 256, 0, stream>>>(proj_w2, w2t, 16384, 7);
    k_t<<<(32768 + 255) / 256, 256, 0, stream>>>(conv_w[0], cwt[0], 32768, 8);
    for (int l = 1; l < 4; ++l)
        k_t<<<(65536 + 255) / 256, 256, 0, stream>>>(conv_w[l], cwt[l], 65536, 8);
    k_t<<<(524288 + 255) / 256, 256, 0, stream>>>(fp_w, fpwt, 524288, 8);
    k_t<<<(65536 + 255) / 256, 256, 0, stream>>>(lin1_w, l1wt, 65536, 7);
    k_cvt<<<(NG * 2048 / 8 + 255) / 256, 256, 0, stream>>>(fingerprint, fpbf, NG * 2048 / 8);

    // --- fingerprint linear, split-K=4 ---
    k_binit<<<NG, 256, 0, stream>>>(fp_emb, fp_b);
    k_mmA<false, false, false, true, false><<<dim3((NG + 127) / 128, 2, 4), 256, 0, stream>>>(
        fpbf, fpwt, fp_emb, nullptr, nullptr, NG, 256, 2048, 512);
    k_z<<<NG, 256, 0, stream>>>(fp_emb, zcat);

    const int mg = (NN + 127) / 128;  // 782

    // --- projector: h1 = relu(gather @ w1 + b1) -> bufA [NN,128] bf16 ---
    k_mm<true, true, true, true><<<dim3(mg, 1), 256, 0, stream>>>(
        nullptr, w1t, bufA, proj_b1, NN, 128, 384,
        atom_idx, degree_idx, charge_idx, emb_atom, emb_degree, emb_charge);
    // --- h0' = (h1 @ w2 + b2) * dinv -> bufB [NN,128] bf16 (prescaled) ---
    k_mmA<true, false, true, false, true><<<dim3(mg, 1), 256, 0, stream>>>(
        bufA, w2t, bufB, proj_b2, dinv, NN, 128, 128, 0);

    // --- layer 0 reordered: agg = (S*h0) -> bufA; h = relu(agg@W0 + b0) -> bufB ---
    k_scat3<1, false><<<NN / 16, 256, 0, stream>>>(bufB, bufA, dinv, row_ptr, colA, nullptr);
    k_mmA<true, true, true, false, false><<<dim3(mg, 2), 256, 0, stream>>>(
        bufA, cwt[0], bufB, conv_b[0], nullptr, NN, 256, 128, 0);

    // --- layers 1-3: xw' = (h@W)*dinv -> bufA; h = relu(S-sum + b) -> bufB ---
    for (int l = 1; l < 4; ++l) {
        k_mmA<false, false, true, false, true><<<dim3(mg, 2), 256, 0, stream>>>(
            bufB, cwt[l], bufA, nullptr, dinv, NN, 256, 256, 0);
        k_scat3<2, true><<<NN / 8, 256, 0, stream>>>(bufA, bufB, dinv, row_ptr, colA, conv_b[l]);
    }

    // --- pooling (bf16 into zcat cols 256..511) ---
    k_bounds<<<(NN + 255) / 256, 256, 0, stream>>>(batch, gstart);
    k_pool<<<NG, 64, 0, stream>>>(bufB, gstart, zcat);

    // --- head: z1 = relu(zcat @ lin1 + b1) (f32), out = z1 . w2 + b2 ---
    k_mmA<true, true, false, false, false><<<dim3((NG + 127) / 128, 1), 256, 0, stream>>>(
        zcat, l1wt, z1, lin1_b, nullptr, NG, 128, 512, 0);
    k_dot<<<NG / 4, 256, 0, stream>>>(z1, lin2_w, lin2_b, out);
}

// Round 9
// 709.501 us; speedup vs baseline: 1.1356x; 1.0557x over previous
//
#include <hip/hip_runtime.h>
#include <stdint.h>

#define NN 100000   // nodes
#define NE 800000   // edges
#define NG 4000     // graphs
#define NBLK ((NN + 255) / 256)   // 391 scan blocks

typedef __attribute__((ext_vector_type(8))) short s16x8;   // 8 bf16 (4 VGPRs)
typedef __attribute__((ext_vector_type(4))) float f32x4;
typedef __attribute__((ext_vector_type(2))) float f32x2;

__device__ __forceinline__ float b2f(unsigned short u) {
    return __uint_as_float(((unsigned int)u) << 16);
}
__device__ __forceinline__ unsigned short f2b(float f) {
    unsigned int x = __float_as_uint(f);
    x = x + 0x7FFFu + ((x >> 16) & 1u);   // RNE
    return (unsigned short)(x >> 16);
}
__device__ __forceinline__ s16x8 cvt8(const float* __restrict__ p) {
    float4 a = *(const float4*)p;
    float4 b = *(const float4*)(p + 4);
    s16x8 r = {(short)f2b(a.x), (short)f2b(a.y), (short)f2b(a.z), (short)f2b(a.w),
               (short)f2b(b.x), (short)f2b(b.y), (short)f2b(b.z), (short)f2b(b.w)};
    return r;
}

// async global->LDS, 16B per lane. LDS dest = wave-uniform base + lane*16.
__device__ __forceinline__ void gload16(const void* g, void* l) {
    __builtin_amdgcn_global_load_lds((const __attribute__((address_space(1))) unsigned int*)g,
                                     (__attribute__((address_space(3))) unsigned int*)l, 16, 0, 0);
}

// accumulate 8 bf16 into 4 f32 pairs via v_pk_add_f32 (2 adds/inst)
__device__ __forceinline__ void acc8(f32x2* acc, s16x8 r) {
    const unsigned int* u = (const unsigned int*)&r;
#pragma unroll
    for (int q = 0; q < 4; ++q) {
        unsigned int w = u[q];
        f32x2 x;
        x[0] = __uint_as_float(w << 16);          // even col (low bf16)
        x[1] = __uint_as_float(w & 0xFFFF0000u);  // odd col (high bf16)
        asm("v_pk_add_f32 %0, %1, %0" : "+v"(acc[q]) : "v"(x));
    }
}

// ---------------- degree / CSR build ----------------
__global__ void k_count(const int* __restrict__ dst, int* __restrict__ cnt) {
    int e = blockIdx.x * 256 + threadIdx.x;
    if (e < NE) atomicAdd(&cnt[dst[e]], 1);
}

__global__ __launch_bounds__(256) void k_bsum(const int* __restrict__ cnt, int* __restrict__ bsum) {
    __shared__ int s[256];
    int i = blockIdx.x * 256 + threadIdx.x;
    s[threadIdx.x] = (i < NN) ? cnt[i] : 0;
    __syncthreads();
    for (int off = 128; off; off >>= 1) {
        if (threadIdx.x < off) s[threadIdx.x] += s[threadIdx.x + off];
        __syncthreads();
    }
    if (threadIdx.x == 0) bsum[blockIdx.x] = s[0];
}

__global__ __launch_bounds__(512) void k_bscan(const int* __restrict__ bsum, int* __restrict__ bpre) {
    __shared__ int s[512];
    int t = threadIdx.x;
    int v = (t < NBLK) ? bsum[t] : 0;
    s[t] = v;
    __syncthreads();
    for (int off = 1; off < 512; off <<= 1) {
        int u = (t >= off) ? s[t - off] : 0;
        __syncthreads();
        s[t] += u;
        __syncthreads();
    }
    if (t < NBLK) bpre[t] = s[t] - v;   // exclusive prefix of block sums
}

// row_ptr + cursor + dinv in one pass
__global__ __launch_bounds__(256) void k_rowptr(const int* __restrict__ cnt, const int* __restrict__ bpre,
                                                int* __restrict__ row_ptr, int* __restrict__ cursor,
                                                float* __restrict__ dinv) {
    __shared__ int s[256];
    int t = threadIdx.x;
    int i = blockIdx.x * 256 + t;
    int v = (i < NN) ? cnt[i] : 0;
    s[t] = v;
    __syncthreads();
    for (int off = 1; off < 256; off <<= 1) {
        int u = (t >= off) ? s[t - off] : 0;
        __syncthreads();
        s[t] += u;
        __syncthreads();
    }
    if (i < NN) {
        int excl = bpre[blockIdx.x] + s[t] - v;
        row_ptr[i] = excl;
        cursor[i] = excl;
        dinv[i] = rsqrtf((float)(v + 1));   // +1 self loop
        if (i == NN - 1) row_ptr[NN] = NE;
    }
}

__global__ void k_fill(const int* __restrict__ src, const int* __restrict__ dst,
                       int* __restrict__ cursor, int* __restrict__ colA) {
    int e = blockIdx.x * 256 + threadIdx.x;
    if (e < NE) {
        int d = dst[e];
        int p = atomicAdd(&cursor[d], 1);
        colA[p] = src[e];
    }
}

// ---------------- fused weight transpose-convert: 7 segments, f32 [K][N] -> bf16 [N][K] ----------------
struct TArgs {
    const float* src[7];
    unsigned short* dst[7];
    int kn[7];
    int ln[7];
    int off[8];   // prefix offsets, off[7] = total
};

__global__ __launch_bounds__(256) void k_prep(TArgs a) {
    int i = blockIdx.x * 256 + threadIdx.x;
    if (i >= a.off[7]) return;
    int s = 0;
    while (i >= a.off[s + 1]) ++s;
    int j = i - a.off[s];
    int k = j >> a.ln[s], n = j & ((1 << a.ln[s]) - 1);
    a.dst[s][(size_t)n * (a.kn[s] >> a.ln[s]) + k] = f2b(a.src[s][j]);
}

// fingerprint f32 -> bf16 (no transpose), 8 elems/thread
__global__ void k_cvt(const float* __restrict__ src, unsigned short* __restrict__ dst, int n8) {
    int i = blockIdx.x * 256 + threadIdx.x;
    if (i < n8) *(s16x8*)&dst[(size_t)i * 8] = cvt8(&src[(size_t)i * 8]);
}

// init fp_emb with bias (split-K GEMM accumulates on top)
__global__ void k_binit(float* __restrict__ fe, const float* __restrict__ b) {
    int i = blockIdx.x * 256 + threadIdx.x;
    fe[i] = b[i & 255];
}

// fp_emb f32 -> zcat bf16 (cols 0..255 of [NG][512])
__global__ void k_z(const float* __restrict__ fe, unsigned short* __restrict__ zcat) {
    int i = blockIdx.x * 256 + threadIdx.x;
    int g = i >> 8, c = i & 255;
    zcat[(size_t)g * 512 + c] = f2b(fe[i]);
}

// ---------------- reg-staged MFMA GEMM with embedding gather (projector layer 1) ----------------
template <bool GATHER, bool BIAS, bool RELU, bool CBF16>
__global__ __launch_bounds__(256) void k_mm(
    const unsigned short* __restrict__ A, const unsigned short* __restrict__ Bt,
    void* __restrict__ Cv, const float* __restrict__ bias, int M, int N, int K,
    const int* __restrict__ ai, const int* __restrict__ di, const int* __restrict__ ci,
    const float* __restrict__ ea, const float* __restrict__ ed, const float* __restrict__ ec) {
    __shared__ unsigned short As[128 * 40];
    __shared__ unsigned short Bs[128 * 40];
    const int tid = threadIdx.x;
    const int row0 = blockIdx.x * 128, col0 = blockIdx.y * 128;
    const int lane = tid & 63, wid = tid >> 6;
    const int wrow = (wid >> 1) * 64, wcol = (wid & 1) * 64;
    const int lr = lane & 15, lk8 = (lane >> 4) * 8;

    const int sr = tid >> 1;
    const int skc = (tid & 1) * 16;
    const int agrow = row0 + sr;
    const int bgrow = col0 + sr;
    int ia = 0, idg = 0, ic = 0;
    if (GATHER && agrow < M) { ia = ai[agrow] * 128; idg = di[agrow] * 128; ic = ci[agrow] * 128; }

    f32x4 acc[4][4] = {};

    for (int kb = 0; kb < K; kb += 32) {
        if (kb) __syncthreads();
#pragma unroll
        for (int c = 0; c < 2; ++c) {
            int kloc = skc + c * 8;
            s16x8 v = {};
            if (agrow < M) {
                if (GATHER) {
                    int kg = kb + kloc;
                    const float* p = (kg < 128) ? (ea + ia + kg)
                                   : (kg < 256) ? (ed + idg + kg - 128)
                                                : (ec + ic + kg - 256);
                    v = cvt8(p);
                } else {
                    v = *(const s16x8*)&A[(size_t)agrow * K + kb + kloc];
                }
            }
            *(s16x8*)&As[sr * 40 + kloc] = v;
            s16x8 w = *(const s16x8*)&Bt[(size_t)bgrow * K + kb + kloc];
            *(s16x8*)&Bs[sr * 40 + kloc] = w;
        }
        __syncthreads();
        s16x8 af[4], bfr[4];
#pragma unroll
        for (int f = 0; f < 4; ++f)
            af[f] = *(const s16x8*)&As[(wrow + f * 16 + lr) * 40 + lk8];
#pragma unroll
        for (int f = 0; f < 4; ++f)
            bfr[f] = *(const s16x8*)&Bs[(wcol + f * 16 + lr) * 40 + lk8];
#pragma unroll
        for (int fm = 0; fm < 4; ++fm)
#pragma unroll
            for (int fn = 0; fn < 4; ++fn)
                acc[fm][fn] = __builtin_amdgcn_mfma_f32_16x16x32_bf16(af[fm], bfr[fn], acc[fm][fn], 0, 0, 0);
    }
#pragma unroll
    for (int fm = 0; fm < 4; ++fm) {
#pragma unroll
        for (int r = 0; r < 4; ++r) {
            int row = row0 + wrow + fm * 16 + (lane >> 4) * 4 + r;
            if (row < M) {
#pragma unroll
                for (int fn = 0; fn < 4; ++fn) {
                    int col = col0 + wcol + fn * 16 + lr;
                    float v = acc[fm][fn][r];
                    if (BIAS) v += bias[col];
                    if (RELU) v = fmaxf(v, 0.f);
                    if (CBF16) ((unsigned short*)Cv)[(size_t)row * N + col] = f2b(v);
                    else       ((float*)Cv)[(size_t)row * N + col] = v;
                }
            }
        }
    }
}

// ---------------- 2-phase double-buffered MFMA GEMM, tile 128x128 ----------------
template <bool BIAS, bool RELU, bool CBF16, bool SPLITK, bool PRES>
__global__ __launch_bounds__(256) void k_mmA(
    const unsigned short* __restrict__ A, const unsigned short* __restrict__ Bt,
    void* __restrict__ Cv, const float* __restrict__ bias, const float* __restrict__ pres,
    int M, int N, int K, int kc) {
    __shared__ unsigned short As[2][128 * 32];
    __shared__ unsigned short Bs[2][128 * 32];
    const int tid = threadIdx.x;
    const int row0 = blockIdx.x * 128, col0 = blockIdx.y * 128;
    const int lane = tid & 63, wid = tid >> 6;
    const int wrow = (wid >> 1) * 64, wcol = (wid & 1) * 64;
    const int lr = lane & 15, lk8 = (lane >> 4) * 8;

    const int k0 = SPLITK ? blockIdx.z * kc : 0;
    const int nt = (SPLITK ? kc : K) / 32;

    const int sra = wid * 32 + (lane >> 2);
    const int sca = (lane & 3) * 8;
    const unsigned short* a0 = A + (size_t)min(row0 + sra, M - 1) * K + sca + k0;
    const unsigned short* a1 = A + (size_t)min(row0 + sra + 16, M - 1) * K + sca + k0;
    const unsigned short* b0 = Bt + (size_t)(col0 + sra) * K + sca + k0;
    const unsigned short* b1 = Bt + (size_t)(col0 + sra + 16) * K + sca + k0;
    const int lo0 = (wid * 2 + 0) * 512;
    const int lo1 = (wid * 2 + 1) * 512;

    f32x4 acc[4][4] = {};

    gload16(a0, &As[0][lo0]);
    gload16(a1, &As[0][lo1]);
    gload16(b0, &Bs[0][lo0]);
    gload16(b1, &Bs[0][lo1]);
    __syncthreads();

    int cur = 0;
    for (int t = 0; t < nt; ++t) {
        if (t + 1 < nt) {
            int kb = (t + 1) * 32;
            gload16(a0 + kb, &As[cur ^ 1][lo0]);
            gload16(a1 + kb, &As[cur ^ 1][lo1]);
            gload16(b0 + kb, &Bs[cur ^ 1][lo0]);
            gload16(b1 + kb, &Bs[cur ^ 1][lo1]);
        }
        s16x8 af[4], bfr[4];
#pragma unroll
        for (int f = 0; f < 4; ++f)
            af[f] = *(const s16x8*)&As[cur][(wrow + f * 16 + lr) * 32 + lk8];
#pragma unroll
        for (int f = 0; f < 4; ++f)
            bfr[f] = *(const s16x8*)&Bs[cur][(wcol + f * 16 + lr) * 32 + lk8];
#pragma unroll
        for (int fm = 0; fm < 4; ++fm)
#pragma unroll
            for (int fn = 0; fn < 4; ++fn)
                acc[fm][fn] = __builtin_amdgcn_mfma_f32_16x16x32_bf16(af[fm], bfr[fn], acc[fm][fn], 0, 0, 0);
        __syncthreads();
        cur ^= 1;
    }
#pragma unroll
    for (int fm = 0; fm < 4; ++fm) {
#pragma unroll
        for (int r = 0; r < 4; ++r) {
            int row = row0 + wrow + fm * 16 + (lane >> 4) * 4 + r;
            if (row < M) {
                float pr = PRES ? pres[row] : 1.f;
#pragma unroll
                for (int fn = 0; fn < 4; ++fn) {
                    int col = col0 + wcol + fn * 16 + lr;
                    float v = acc[fm][fn][r];
                    if (SPLITK) {
                        atomicAdd(&((float*)Cv)[(size_t)row * N + col], v);
                    } else {
                        if (BIAS) v += bias[col];
                        if (RELU) v = fmaxf(v, 0.f);
                        if (PRES) v *= pr;
                        if (CBF16) ((unsigned short*)Cv)[(size_t)row * N + col] = f2b(v);
                        else       ((float*)Cv)[(size_t)row * N + col] = v;
                    }
                }
            }
        }
    }
}

// ---------------- 2-phase dbuf MFMA GEMM, tile 128x256 (N==256 exactly) ----------------
// 512 thr / 8 waves (2x4); halves A-matrix traffic vs two 128x128 col-blocks.
// Staging: 24 x 1KB chunks per K-step (A:8, B:16); wave w handles chunks {w, 8+w, 16+w}.
template <bool BIAS, bool RELU, bool CBF16, bool PRES>
__global__ __launch_bounds__(512) void k_mmB(
    const unsigned short* __restrict__ A, const unsigned short* __restrict__ Bt,
    void* __restrict__ Cv, const float* __restrict__ bias, const float* __restrict__ pres,
    int M, int K) {
    constexpr int N = 256;
    __shared__ unsigned short As[2][128 * 32];
    __shared__ unsigned short Bs[2][256 * 32];
    const int tid = threadIdx.x;
    const int row0 = blockIdx.x * 128;
    const int lane = tid & 63, wid = tid >> 6;          // wid 0..7
    const int wrow = (wid >> 2) * 64, wcol = (wid & 3) * 64;
    const int lr = lane & 15, lk8 = (lane >> 4) * 8;

    const int nt = K / 32;

    const int rsub = lane >> 2;        // 0..15
    const int csub = (lane & 3) * 8;
    const unsigned short* ga  = A  + (size_t)min(row0 + wid * 16 + rsub, M - 1) * K + csub;
    const unsigned short* gb0 = Bt + (size_t)(wid * 16 + rsub) * K + csub;
    const unsigned short* gb1 = Bt + (size_t)(128 + wid * 16 + rsub) * K + csub;
    const int la  = wid * 512;
    const int lb0 = wid * 512;
    const int lb1 = (8 + wid) * 512;

    f32x4 acc[4][4] = {};

    gload16(ga, &As[0][la]);
    gload16(gb0, &Bs[0][lb0]);
    gload16(gb1, &Bs[0][lb1]);
    __syncthreads();

    int cur = 0;
    for (int t = 0; t < nt; ++t) {
        if (t + 1 < nt) {
            int kb = (t + 1) * 32;
            gload16(ga + kb, &As[cur ^ 1][la]);
            gload16(gb0 + kb, &Bs[cur ^ 1][lb0]);
            gload16(gb1 + kb, &Bs[cur ^ 1][lb1]);
        }
        s16x8 af[4], bfr[4];
#pragma unroll
        for (int f = 0; f < 4; ++f)
            af[f] = *(const s16x8*)&As[cur][(wrow + f * 16 + lr) * 32 + lk8];
#pragma unroll
        for (int f = 0; f < 4; ++f)
            bfr[f] = *(const s16x8*)&Bs[cur][(wcol + f * 16 + lr) * 32 + lk8];
#pragma unroll
        for (int fm = 0; fm < 4; ++fm)
#pragma unroll
            for (int fn = 0; fn < 4; ++fn)
                acc[fm][fn] = __builtin_amdgcn_mfma_f32_16x16x32_bf16(af[fm], bfr[fn], acc[fm][fn], 0, 0, 0);
        __syncthreads();
        cur ^= 1;
    }
#pragma unroll
    for (int fm = 0; fm < 4; ++fm) {
#pragma unroll
        for (int r = 0; r < 4; ++r) {
            int row = row0 + wrow + fm * 16 + (lane >> 4) * 4 + r;
            if (row < M) {
                float pr = PRES ? pres[row] : 1.f;
#pragma unroll
                for (int fn = 0; fn < 4; ++fn) {
                    int col = wcol + fn * 16 + lr;
                    float v = acc[fm][fn][r];
                    if (BIAS) v += bias[col];
                    if (RELU) v = fmaxf(v, 0.f);
                    if (PRES) v *= pr;
                    if (CBF16) ((unsigned short*)Cv)[(size_t)row * N + col] = f2b(v);
                    else       ((float*)Cv)[(size_t)row * N + col] = v;
                }
            }
        }
    }
}

// ---------------- GCN aggregate on dinv-PRESCALED rows, group-per-node, unroll 4 ----------------
template <int WPN, bool FUSE>
__global__ __launch_bounds__(256) void k_scat3(const unsigned short* __restrict__ xw,
                                               unsigned short* __restrict__ hout,
                                               const float* __restrict__ dinv,
                                               const int* __restrict__ row_ptr,
                                               const int* __restrict__ colA,
                                               const float* __restrict__ bias) {
    constexpr int W = WPN * 128;     // feature width
    constexpr int NPW = 4 / WPN;     // nodes per wave
    const int wid = threadIdx.x >> 6, lane = threadIdx.x & 63;
    const int grp = lane >> 4, li = lane & 15;
    const int v = (blockIdx.x * 4 + wid) * NPW + grp / WPN;   // NN % (4*NPW) == 0
    const int cs = (WPN == 2) ? (grp & 1) * 128 : 0;
    const int c0 = cs + li * 8;

    // hoisted: independent of edge loop
    const float dv = dinv[v];
    s16x8 rs = *(const s16x8*)&xw[(size_t)v * W + c0];   // self (prescaled)

    f32x2 acc[4] = {};
    const int beg = row_ptr[v], end = row_ptr[v + 1];
    int p = beg;
    for (; p + 3 < end; p += 4) {
        int s0 = colA[p], s1 = colA[p + 1], s2 = colA[p + 2], s3 = colA[p + 3];
        s16x8 r0 = *(const s16x8*)&xw[(size_t)s0 * W + c0];
        s16x8 r1 = *(const s16x8*)&xw[(size_t)s1 * W + c0];
        s16x8 r2 = *(const s16x8*)&xw[(size_t)s2 * W + c0];
        s16x8 r3 = *(const s16x8*)&xw[(size_t)s3 * W + c0];
        acc8(acc, r0);
        acc8(acc, r1);
        acc8(acc, r2);
        acc8(acc, r3);
    }
    for (; p < end; ++p) {
        s16x8 r0 = *(const s16x8*)&xw[(size_t)colA[p] * W + c0];
        acc8(acc, r0);
    }

    unsigned short o[8];
#pragma unroll
    for (int j = 0; j < 8; ++j) {
        float a = acc[j >> 1][j & 1];
        a += b2f((unsigned short)rs[j]);
        a *= dv;
        if (FUSE) a = fmaxf(a + bias[c0 + j], 0.f);
        o[j] = f2b(a);
    }
    *(s16x8*)&hout[(size_t)v * W + c0] = *(const s16x8*)o;
}

// ---------------- graph boundaries from sorted batch ----------------
__global__ void k_bounds(const int* __restrict__ batch, int* __restrict__ gstart) {
    int n = blockIdx.x * 256 + threadIdx.x;
    if (n >= NN) return;
    int b = batch[n];
    if (n == 0) {
        for (int g = 0; g <= b; ++g) gstart[g] = 0;
    } else {
        int pb = batch[n - 1];
        if (pb != b)
            for (int g = pb + 1; g <= b; ++g) gstart[g] = n;
    }
    if (n == NN - 1) {
        for (int g = b + 1; g <= NG; ++g) gstart[g] = NN;
    }
}

// ---------------- pooling: bf16 sums into zcat cols 256..511 ----------------
__global__ __launch_bounds__(64) void k_pool(const unsigned short* __restrict__ h,
                                             const int* __restrict__ gstart,
                                             unsigned short* __restrict__ zcat) {
    int g = blockIdx.x;
    int lane = threadIdx.x;
    int c0 = lane * 4;
    int beg = gstart[g], end = gstart[g + 1];
    float a0 = 0.f, a1 = 0.f, a2 = 0.f, a3 = 0.f;
    for (int n = beg; n < end; ++n) {
        ushort4 r = *(const ushort4*)&h[(size_t)n * 256 + c0];
        a0 += b2f(r.x); a1 += b2f(r.y); a2 += b2f(r.z); a3 += b2f(r.w);
    }
    ushort4 o;
    o.x = f2b(a0); o.y = f2b(a1); o.z = f2b(a2); o.w = f2b(a3);
    *(ushort4*)&zcat[(size_t)g * 512 + 256 + c0] = o;
}

// ---------------- final dot: out[g] = z1[g] . w2 + b2 ----------------
__global__ __launch_bounds__(256) void k_dot(const float* __restrict__ z1,
                                             const float* __restrict__ w2,
                                             const float* __restrict__ b2,
                                             float* __restrict__ out) {
    int wid = threadIdx.x >> 6, lane = threadIdx.x & 63;
    int g = blockIdx.x * 4 + wid;   // NG % 4 == 0
    float s = z1[(size_t)g * 128 + lane] * w2[lane]
            + z1[(size_t)g * 128 + 64 + lane] * w2[64 + lane];
#pragma unroll
    for (int off = 32; off; off >>= 1) s += __shfl_xor(s, off);
    if (lane == 0) out[g] = s + b2[0];
}

// ---------------- launch ----------------
extern "C" void kernel_launch(void* const* d_in, const int* in_sizes, int n_in,
                              void* d_out, int out_size, void* d_ws, size_t ws_size,
                              hipStream_t stream) {
    const int* atom_idx   = (const int*)d_in[0];
    const int* degree_idx = (const int*)d_in[1];
    const int* charge_idx = (const int*)d_in[2];
    const int* edge_index = (const int*)d_in[3];
    const int* batch      = (const int*)d_in[4];
    const float* fingerprint = (const float*)d_in[5];
    const float* emb_atom   = (const float*)d_in[6];
    const float* emb_degree = (const float*)d_in[7];
    const float* emb_charge = (const float*)d_in[8];
    const float* proj_w1 = (const float*)d_in[9];
    const float* proj_b1 = (const float*)d_in[10];
    const float* proj_w2 = (const float*)d_in[11];
    const float* proj_b2 = (const float*)d_in[12];
    const float* fp_w = (const float*)d_in[13];
    const float* fp_b = (const float*)d_in[14];
    const float* conv_w[4] = {(const float*)d_in[15], (const float*)d_in[17],
                              (const float*)d_in[19], (const float*)d_in[21]};
    const float* conv_b[4] = {(const float*)d_in[16], (const float*)d_in[18],
                              (const float*)d_in[20], (const float*)d_in[22]};
    const float* lin1_w = (const float*)d_in[23];
    const float* lin1_b = (const float*)d_in[24];
    const float* lin2_w = (const float*)d_in[25];
    const float* lin2_b = (const float*)d_in[26];
    float* out = (float*)d_out;

    const int* src = edge_index;
    const int* dst = edge_index + NE;

    // workspace carve (256B aligned)
    char* p = (char*)d_ws;
    auto carve = [&](size_t bytes) { void* r = (void*)p; p += (bytes + 255) & ~(size_t)255; return r; };
    unsigned short* bufA = (unsigned short*)carve((size_t)NN * 256 * 2);
    unsigned short* bufB = (unsigned short*)carve((size_t)NN * 256 * 2);
    int*   cnt     = (int*)carve((size_t)NN * 4);
    float* dinv    = (float*)carve((size_t)NN * 4);
    int*   row_ptr = (int*)carve((size_t)(NN + 1) * 4);
    int*   cursor  = (int*)carve((size_t)(NN + 1) * 4);
    int*   colA    = (int*)carve((size_t)NE * 4);
    int*   gstart  = (int*)carve((size_t)(NG + 1) * 4);
    float* fp_emb  = (float*)carve((size_t)NG * 256 * 4);
    int*   bsum    = (int*)carve((size_t)NBLK * 4);
    int*   bpre    = (int*)carve((size_t)NBLK * 4);
    unsigned short* w1t  = (unsigned short*)carve((size_t)128 * 384 * 2);
    unsigned short* w2t  = (unsigned short*)carve((size_t)128 * 128 * 2);
    unsigned short* cwt[4];
    cwt[0] = (unsigned short*)carve((size_t)256 * 128 * 2);
    for (int l = 1; l < 4; ++l) cwt[l] = (unsigned short*)carve((size_t)256 * 256 * 2);
    unsigned short* fpwt = (unsigned short*)carve((size_t)256 * 2048 * 2);
    unsigned short* fpbf = (unsigned short*)carve((size_t)NG * 2048 * 2);
    unsigned short* l1wt = (unsigned short*)carve((size_t)128 * 512 * 2);
    unsigned short* zcat = (unsigned short*)carve((size_t)NG * 512 * 2);
    float* z1      = (float*)carve((size_t)NG * 128 * 4);

    // --- CSR build (parallel scan; dinv fused into rowptr) ---
    hipMemsetAsync(cnt, 0, (size_t)NN * 4, stream);
    k_count<<<(NE + 255) / 256, 256, 0, stream>>>(dst, cnt);
    k_bsum<<<NBLK, 256, 0, stream>>>(cnt, bsum);
    k_bscan<<<1, 512, 0, stream>>>(bsum, bpre);
    k_rowptr<<<NBLK, 256, 0, stream>>>(cnt, bpre, row_ptr, cursor, dinv);
    k_fill<<<(NE + 255) / 256, 256, 0, stream>>>(src, dst, cursor, colA);

    // --- fused weight transpose-converts (f32 [K][N] -> bf16 [N][K]) ---
    {
        TArgs a;
        const float* s7[7] = {proj_w1, proj_w2, conv_w[0], conv_w[1], conv_w[2], conv_w[3], fp_w};
        unsigned short* d7[7] = {w1t, w2t, cwt[0], cwt[1], cwt[2], cwt[3], fpwt};
        int kn7[7] = {49152, 16384, 32768, 65536, 65536, 65536, 524288};
        int ln7[7] = {7, 7, 8, 8, 8, 8, 8};
        int o = 0;
        for (int s = 0; s < 7; ++s) { a.src[s] = s7[s]; a.dst[s] = d7[s]; a.kn[s] = kn7[s]; a.ln[s] = ln7[s]; a.off[s] = o; o += kn7[s]; }
        a.off[7] = o;   // 819200... plus l1w separate below
        k_prep<<<(o + 255) / 256, 256, 0, stream>>>(a);
    }
    // lin1 transpose (kept separate: 8th segment)
    {
        TArgs a;
        a.src[0] = lin1_w; a.dst[0] = l1wt; a.kn[0] = 65536; a.ln[0] = 7; a.off[0] = 0;
        for (int s = 1; s < 7; ++s) { a.src[s] = lin1_w; a.dst[s] = l1wt; a.kn[s] = 0; a.ln[s] = 0; a.off[s] = 65536; }
        a.off[7] = 65536;
        k_prep<<<(65536 + 255) / 256, 256, 0, stream>>>(a);
    }
    k_cvt<<<(NG * 2048 / 8 + 255) / 256, 256, 0, stream>>>(fingerprint, fpbf, NG * 2048 / 8);

    // --- fingerprint linear, split-K=4 ---
    k_binit<<<NG, 256, 0, stream>>>(fp_emb, fp_b);
    k_mmA<false, false, false, true, false><<<dim3((NG + 127) / 128, 2, 4), 256, 0, stream>>>(
        fpbf, fpwt, fp_emb, nullptr, nullptr, NG, 256, 2048, 512);
    k_z<<<NG, 256, 0, stream>>>(fp_emb, zcat);

    const int mg = (NN + 127) / 128;  // 782

    // --- projector: h1 = relu(gather @ w1 + b1) -> bufA [NN,128] bf16 ---
    k_mm<true, true, true, true><<<dim3(mg, 1), 256, 0, stream>>>(
        nullptr, w1t, bufA, proj_b1, NN, 128, 384,
        atom_idx, degree_idx, charge_idx, emb_atom, emb_degree, emb_charge);
    // --- h0' = (h1 @ w2 + b2) * dinv -> bufB [NN,128] bf16 (prescaled) ---
    k_mmA<true, false, true, false, true><<<dim3(mg, 1), 256, 0, stream>>>(
        bufA, w2t, bufB, proj_b2, dinv, NN, 128, 128, 0);

    // --- layer 0 reordered: agg = (S*h0) -> bufA; h = relu(agg@W0 + b0) -> bufB ---
    k_scat3<1, false><<<NN / 16, 256, 0, stream>>>(bufB, bufA, dinv, row_ptr, colA, nullptr);
    k_mmB<true, true, true, false><<<mg, 512, 0, stream>>>(
        bufA, cwt[0], bufB, conv_b[0], nullptr, NN, 128);

    // --- layers 1-3: xw' = (h@W)*dinv -> bufA; h = relu(S-sum + b) -> bufB ---
    for (int l = 1; l < 4; ++l) {
        k_mmB<false, false, true, true><<<mg, 512, 0, stream>>>(
            bufB, cwt[l], bufA, nullptr, dinv, NN, 256);
        k_scat3<2, true><<<NN / 8, 256, 0, stream>>>(bufA, bufB, dinv, row_ptr, colA, conv_b[l]);
    }

    // --- pooling (bf16 into zcat cols 256..511) ---
    k_bounds<<<(NN + 255) / 256, 256, 0, stream>>>(batch, gstart);
    k_pool<<<NG, 64, 0, stream>>>(bufB, gstart, zcat);

    // --- head: z1 = relu(zcat @ lin1 + b1) (f32), out = z1 . w2 + b2 ---
    k_mmA<true, true, false, false, false><<<dim3((NG + 127) / 128, 1), 256, 0, stream>>>(
        zcat, l1wt, z1, lin1_b, nullptr, NG, 128, 512, 0);
    k_dot<<<NG / 4, 256, 0, stream>>>(z1, lin2_w, lin2_b, out);
}

// Round 10
// 681.391 us; speedup vs baseline: 1.1825x; 1.0413x over previous
//
#include <hip/hip_runtime.h>
#include <stdint.h>

#define NN 100000   // nodes
#define NE 800000   // edges
#define NG 4000     // graphs
#define NBLK ((NN + 255) / 256)   // 391 scan blocks

typedef __attribute__((ext_vector_type(8))) short s16x8;   // 8 bf16 (4 VGPRs)
typedef __attribute__((ext_vector_type(4))) float f32x4;
typedef __attribute__((ext_vector_type(2))) float f32x2;

__device__ __forceinline__ float b2f(unsigned short u) {
    return __uint_as_float(((unsigned int)u) << 16);
}
__device__ __forceinline__ unsigned short f2b(float f) {
    unsigned int x = __float_as_uint(f);
    x = x + 0x7FFFu + ((x >> 16) & 1u);   // RNE
    return (unsigned short)(x >> 16);
}
__device__ __forceinline__ s16x8 cvt8(const float* __restrict__ p) {
    float4 a = *(const float4*)p;
    float4 b = *(const float4*)(p + 4);
    s16x8 r = {(short)f2b(a.x), (short)f2b(a.y), (short)f2b(a.z), (short)f2b(a.w),
               (short)f2b(b.x), (short)f2b(b.y), (short)f2b(b.z), (short)f2b(b.w)};
    return r;
}

// async global->LDS, 16B per lane. LDS dest = wave-uniform base + lane*16.
__device__ __forceinline__ void gload16(const void* g, void* l) {
    __builtin_amdgcn_global_load_lds((const __attribute__((address_space(1))) unsigned int*)g,
                                     (__attribute__((address_space(3))) unsigned int*)l, 16, 0, 0);
}

// accumulate 8 bf16 into 4 f32 pairs via v_pk_add_f32 (2 adds/inst)
__device__ __forceinline__ void acc8(f32x2* acc, s16x8 r) {
    const unsigned int* u = (const unsigned int*)&r;
#pragma unroll
    for (int q = 0; q < 4; ++q) {
        unsigned int w = u[q];
        f32x2 x;
        x[0] = __uint_as_float(w << 16);          // even col (low bf16)
        x[1] = __uint_as_float(w & 0xFFFF0000u);  // odd col (high bf16)
        asm("v_pk_add_f32 %0, %1, %0" : "+v"(acc[q]) : "v"(x));
    }
}

// ---------------- degree / CSR build ----------------
__global__ void k_count(const int* __restrict__ dst, int* __restrict__ cnt) {
    int e = blockIdx.x * 256 + threadIdx.x;
    if (e < NE) atomicAdd(&cnt[dst[e]], 1);
}

__global__ __launch_bounds__(256) void k_bsum(const int* __restrict__ cnt, int* __restrict__ bsum) {
    __shared__ int s[256];
    int i = blockIdx.x * 256 + threadIdx.x;
    s[threadIdx.x] = (i < NN) ? cnt[i] : 0;
    __syncthreads();
    for (int off = 128; off; off >>= 1) {
        if (threadIdx.x < off) s[threadIdx.x] += s[threadIdx.x + off];
        __syncthreads();
    }
    if (threadIdx.x == 0) bsum[blockIdx.x] = s[0];
}

__global__ __launch_bounds__(512) void k_bscan(const int* __restrict__ bsum, int* __restrict__ bpre) {
    __shared__ int s[512];
    int t = threadIdx.x;
    int v = (t < NBLK) ? bsum[t] : 0;
    s[t] = v;
    __syncthreads();
    for (int off = 1; off < 512; off <<= 1) {
        int u = (t >= off) ? s[t - off] : 0;
        __syncthreads();
        s[t] += u;
        __syncthreads();
    }
    if (t < NBLK) bpre[t] = s[t] - v;   // exclusive prefix of block sums
}

// row_ptr + cursor + dinv in one pass
__global__ __launch_bounds__(256) void k_rowptr(const int* __restrict__ cnt, const int* __restrict__ bpre,
                                                int* __restrict__ row_ptr, int* __restrict__ cursor,
                                                float* __restrict__ dinv) {
    __shared__ int s[256];
    int t = threadIdx.x;
    int i = blockIdx.x * 256 + t;
    int v = (i < NN) ? cnt[i] : 0;
    s[t] = v;
    __syncthreads();
    for (int off = 1; off < 256; off <<= 1) {
        int u = (t >= off) ? s[t - off] : 0;
        __syncthreads();
        s[t] += u;
        __syncthreads();
    }
    if (i < NN) {
        int excl = bpre[blockIdx.x] + s[t] - v;
        row_ptr[i] = excl;
        cursor[i] = excl;
        dinv[i] = rsqrtf((float)(v + 1));   // +1 self loop
        if (i == NN - 1) row_ptr[NN] = NE;
    }
}

__global__ void k_fill(const int* __restrict__ src, const int* __restrict__ dst,
                       int* __restrict__ cursor, int* __restrict__ colA) {
    int e = blockIdx.x * 256 + threadIdx.x;
    if (e < NE) {
        int d = dst[e];
        int p = atomicAdd(&cursor[d], 1);
        colA[p] = src[e];
    }
}

// ---------------- fused weight transpose-convert: 7 segments, f32 [K][N] -> bf16 [N][K] ----------------
struct TArgs {
    const float* src[7];
    unsigned short* dst[7];
    int kn[7];
    int ln[7];
    int off[8];   // prefix offsets, off[7] = total
};

__global__ __launch_bounds__(256) void k_prep(TArgs a) {
    int i = blockIdx.x * 256 + threadIdx.x;
    if (i >= a.off[7]) return;
    int s = 0;
    while (i >= a.off[s + 1]) ++s;
    int j = i - a.off[s];
    int k = j >> a.ln[s], n = j & ((1 << a.ln[s]) - 1);
    a.dst[s][(size_t)n * (a.kn[s] >> a.ln[s]) + k] = f2b(a.src[s][j]);
}

// f32 -> bf16 (no transpose), 8 elems/thread
__global__ void k_cvt(const float* __restrict__ src, unsigned short* __restrict__ dst, int n8) {
    int i = blockIdx.x * 256 + threadIdx.x;
    if (i < n8) *(s16x8*)&dst[(size_t)i * 8] = cvt8(&src[(size_t)i * 8]);
}

// ---------------- projector linearization: Tcat[142][128] + fused head bias b1p ----------------
// Tcat rows 0..119 = ea@W1[0:128], 120..131 = ed@W1[128:256], 132..141 = ec@W1[256:384]
// b1p[j] = lin1_b[j] + sum_c fp_b[c]*lin1_w[c][j]
__global__ __launch_bounds__(256) void k_tab(const float* __restrict__ ea, const float* __restrict__ ed,
                                             const float* __restrict__ ec, const float* __restrict__ w1,
                                             const float* __restrict__ fpb, const float* __restrict__ l1w,
                                             const float* __restrict__ l1b,
                                             float* __restrict__ Tcat, float* __restrict__ b1p) {
    int i = blockIdx.x * 256 + threadIdx.x;
    if (i < 142 * 128) {
        int r = i >> 7, j = i & 127;
        const float* src; int off, lr;
        if (r < 120)      { src = ea; off = 0;   lr = r; }
        else if (r < 132) { src = ed; off = 128; lr = r - 120; }
        else              { src = ec; off = 256; lr = r - 132; }
        float s = 0.f;
        for (int k = 0; k < 128; ++k)
            s = fmaf(src[lr * 128 + k], w1[(off + k) * 128 + j], s);
        Tcat[i] = s;
    } else if (i < 142 * 128 + 128) {
        int j = i - 142 * 128;
        float s = l1b[j];
        for (int c = 0; c < 256; ++c)
            s = fmaf(fpb[c], l1w[c * 128 + j], s);
        b1p[j] = s;
    }
}

// h1[n] = relu(Tcat[ai]+Tcat[120+di]+Tcat[132+ci]+b1) -> bf16 [NN][128]
__global__ __launch_bounds__(256) void k_emb(const int* __restrict__ ai, const int* __restrict__ di,
                                             const int* __restrict__ ci, const float* __restrict__ Tcat,
                                             const float* __restrict__ b1, unsigned short* __restrict__ h1) {
    int i = blockIdx.x * 256 + threadIdx.x;   // NN*16
    if (i >= NN * 16) return;
    int n = i >> 4, c8 = (i & 15) * 8;
    int a = ai[n], d = di[n], c = ci[n];
    const float* ta = Tcat + a * 128 + c8;
    const float* td = Tcat + (120 + d) * 128 + c8;
    const float* tc = Tcat + (132 + c) * 128 + c8;
    unsigned short o[8];
#pragma unroll
    for (int j = 0; j < 8; ++j) {
        float v = ta[j] + td[j] + tc[j] + b1[c8 + j];
        o[j] = f2b(fmaxf(v, 0.f));
    }
    *(s16x8*)&h1[(size_t)n * 128 + c8] = *(const s16x8*)o;
}

// ---------------- 2-phase double-buffered MFMA GEMM, tile 128x128 ----------------
template <bool BIAS, bool RELU, bool CBF16, bool SPLITK, bool PRES>
__global__ __launch_bounds__(256) void k_mmA(
    const unsigned short* __restrict__ A, const unsigned short* __restrict__ Bt,
    void* __restrict__ Cv, const float* __restrict__ bias, const float* __restrict__ pres,
    int M, int N, int K, int kc) {
    __shared__ unsigned short As[2][128 * 32];
    __shared__ unsigned short Bs[2][128 * 32];
    const int tid = threadIdx.x;
    const int row0 = blockIdx.x * 128, col0 = blockIdx.y * 128;
    const int lane = tid & 63, wid = tid >> 6;
    const int wrow = (wid >> 1) * 64, wcol = (wid & 1) * 64;
    const int lr = lane & 15, lk8 = (lane >> 4) * 8;

    const int k0 = SPLITK ? blockIdx.z * kc : 0;
    const int nt = (SPLITK ? kc : K) / 32;

    const int sra = wid * 32 + (lane >> 2);
    const int sca = (lane & 3) * 8;
    const unsigned short* a0 = A + (size_t)min(row0 + sra, M - 1) * K + sca + k0;
    const unsigned short* a1 = A + (size_t)min(row0 + sra + 16, M - 1) * K + sca + k0;
    const unsigned short* b0 = Bt + (size_t)(col0 + sra) * K + sca + k0;
    const unsigned short* b1 = Bt + (size_t)(col0 + sra + 16) * K + sca + k0;
    const int lo0 = (wid * 2 + 0) * 512;
    const int lo1 = (wid * 2 + 1) * 512;

    f32x4 acc[4][4] = {};

    gload16(a0, &As[0][lo0]);
    gload16(a1, &As[0][lo1]);
    gload16(b0, &Bs[0][lo0]);
    gload16(b1, &Bs[0][lo1]);
    __syncthreads();

    int cur = 0;
    for (int t = 0; t < nt; ++t) {
        if (t + 1 < nt) {
            int kb = (t + 1) * 32;
            gload16(a0 + kb, &As[cur ^ 1][lo0]);
            gload16(a1 + kb, &As[cur ^ 1][lo1]);
            gload16(b0 + kb, &Bs[cur ^ 1][lo0]);
            gload16(b1 + kb, &Bs[cur ^ 1][lo1]);
        }
        s16x8 af[4], bfr[4];
#pragma unroll
        for (int f = 0; f < 4; ++f)
            af[f] = *(const s16x8*)&As[cur][(wrow + f * 16 + lr) * 32 + lk8];
#pragma unroll
        for (int f = 0; f < 4; ++f)
            bfr[f] = *(const s16x8*)&Bs[cur][(wcol + f * 16 + lr) * 32 + lk8];
#pragma unroll
        for (int fm = 0; fm < 4; ++fm)
#pragma unroll
            for (int fn = 0; fn < 4; ++fn)
                acc[fm][fn] = __builtin_amdgcn_mfma_f32_16x16x32_bf16(af[fm], bfr[fn], acc[fm][fn], 0, 0, 0);
        __syncthreads();
        cur ^= 1;
    }
#pragma unroll
    for (int fm = 0; fm < 4; ++fm) {
#pragma unroll
        for (int r = 0; r < 4; ++r) {
            int row = row0 + wrow + fm * 16 + (lane >> 4) * 4 + r;
            if (row < M) {
                float pr = PRES ? pres[row] : 1.f;
#pragma unroll
                for (int fn = 0; fn < 4; ++fn) {
                    int col = col0 + wcol + fn * 16 + lr;
                    float v = acc[fm][fn][r];
                    if (SPLITK) {
                        atomicAdd(&((float*)Cv)[(size_t)row * N + col], v);
                    } else {
                        if (BIAS) v += bias[col];
                        if (RELU) v = fmaxf(v, 0.f);
                        if (PRES) v *= pr;
                        if (CBF16) ((unsigned short*)Cv)[(size_t)row * N + col] = f2b(v);
                        else       ((float*)Cv)[(size_t)row * N + col] = v;
                    }
                }
            }
        }
    }
}

// ---------------- 2-phase dbuf MFMA GEMM, tile 128x256 (N==256 exactly) ----------------
template <bool BIAS, bool RELU, bool CBF16, bool PRES>
__global__ __launch_bounds__(512) void k_mmB(
    const unsigned short* __restrict__ A, const unsigned short* __restrict__ Bt,
    void* __restrict__ Cv, const float* __restrict__ bias, const float* __restrict__ pres,
    int M, int K) {
    constexpr int N = 256;
    __shared__ unsigned short As[2][128 * 32];
    __shared__ unsigned short Bs[2][256 * 32];
    const int tid = threadIdx.x;
    const int row0 = blockIdx.x * 128;
    const int lane = tid & 63, wid = tid >> 6;          // wid 0..7
    const int wrow = (wid >> 2) * 64, wcol = (wid & 3) * 64;
    const int lr = lane & 15, lk8 = (lane >> 4) * 8;

    const int nt = K / 32;

    const int rsub = lane >> 2;        // 0..15
    const int csub = (lane & 3) * 8;
    const unsigned short* ga  = A  + (size_t)min(row0 + wid * 16 + rsub, M - 1) * K + csub;
    const unsigned short* gb0 = Bt + (size_t)(wid * 16 + rsub) * K + csub;
    const unsigned short* gb1 = Bt + (size_t)(128 + wid * 16 + rsub) * K + csub;
    const int la  = wid * 512;
    const int lb0 = wid * 512;
    const int lb1 = (8 + wid) * 512;

    f32x4 acc[4][4] = {};

    gload16(ga, &As[0][la]);
    gload16(gb0, &Bs[0][lb0]);
    gload16(gb1, &Bs[0][lb1]);
    __syncthreads();

    int cur = 0;
    for (int t = 0; t < nt; ++t) {
        if (t + 1 < nt) {
            int kb = (t + 1) * 32;
            gload16(ga + kb, &As[cur ^ 1][la]);
            gload16(gb0 + kb, &Bs[cur ^ 1][lb0]);
            gload16(gb1 + kb, &Bs[cur ^ 1][lb1]);
        }
        s16x8 af[4], bfr[4];
#pragma unroll
        for (int f = 0; f < 4; ++f)
            af[f] = *(const s16x8*)&As[cur][(wrow + f * 16 + lr) * 32 + lk8];
#pragma unroll
        for (int f = 0; f < 4; ++f)
            bfr[f] = *(const s16x8*)&Bs[cur][(wcol + f * 16 + lr) * 32 + lk8];
#pragma unroll
        for (int fm = 0; fm < 4; ++fm)
#pragma unroll
            for (int fn = 0; fn < 4; ++fn)
                acc[fm][fn] = __builtin_amdgcn_mfma_f32_16x16x32_bf16(af[fm], bfr[fn], acc[fm][fn], 0, 0, 0);
        __syncthreads();
        cur ^= 1;
    }
#pragma unroll
    for (int fm = 0; fm < 4; ++fm) {
#pragma unroll
        for (int r = 0; r < 4; ++r) {
            int row = row0 + wrow + fm * 16 + (lane >> 4) * 4 + r;
            if (row < M) {
                float pr = PRES ? pres[row] : 1.f;
#pragma unroll
                for (int fn = 0; fn < 4; ++fn) {
                    int col = wcol + fn * 16 + lr;
                    float v = acc[fm][fn][r];
                    if (BIAS) v += bias[col];
                    if (RELU) v = fmaxf(v, 0.f);
                    if (PRES) v *= pr;
                    if (CBF16) ((unsigned short*)Cv)[(size_t)row * N + col] = f2b(v);
                    else       ((float*)Cv)[(size_t)row * N + col] = v;
                }
            }
        }
    }
}

// ---------------- GCN aggregate on dinv-PRESCALED rows, group-per-node, unroll 4 ----------------
template <int WPN, bool FUSE>
__global__ __launch_bounds__(256) void k_scat3(const unsigned short* __restrict__ xw,
                                               unsigned short* __restrict__ hout,
                                               const float* __restrict__ dinv,
                                               const int* __restrict__ row_ptr,
                                               const int* __restrict__ colA,
                                               const float* __restrict__ bias) {
    constexpr int W = WPN * 128;     // feature width
    constexpr int NPW = 4 / WPN;     // nodes per wave
    const int wid = threadIdx.x >> 6, lane = threadIdx.x & 63;
    const int grp = lane >> 4, li = lane & 15;
    const int v = (blockIdx.x * 4 + wid) * NPW + grp / WPN;
    const int cs = (WPN == 2) ? (grp & 1) * 128 : 0;
    const int c0 = cs + li * 8;

    const float dv = dinv[v];
    s16x8 rs = *(const s16x8*)&xw[(size_t)v * W + c0];   // self (prescaled)

    f32x2 acc[4] = {};
    const int beg = row_ptr[v], end = row_ptr[v + 1];
    int p = beg;
    for (; p + 3 < end; p += 4) {
        int s0 = colA[p], s1 = colA[p + 1], s2 = colA[p + 2], s3 = colA[p + 3];
        s16x8 r0 = *(const s16x8*)&xw[(size_t)s0 * W + c0];
        s16x8 r1 = *(const s16x8*)&xw[(size_t)s1 * W + c0];
        s16x8 r2 = *(const s16x8*)&xw[(size_t)s2 * W + c0];
        s16x8 r3 = *(const s16x8*)&xw[(size_t)s3 * W + c0];
        acc8(acc, r0);
        acc8(acc, r1);
        acc8(acc, r2);
        acc8(acc, r3);
    }
    for (; p < end; ++p) {
        s16x8 r0 = *(const s16x8*)&xw[(size_t)colA[p] * W + c0];
        acc8(acc, r0);
    }

    unsigned short o[8];
#pragma unroll
    for (int j = 0; j < 8; ++j) {
        float a = acc[j >> 1][j & 1];
        a += b2f((unsigned short)rs[j]);
        a *= dv;
        if (FUSE) a = fmaxf(a + bias[c0 + j], 0.f);
        o[j] = f2b(a);
    }
    *(s16x8*)&hout[(size_t)v * W + c0] = *(const s16x8*)o;
}

// ---------------- graph boundaries from sorted batch ----------------
__global__ void k_bounds(const int* __restrict__ batch, int* __restrict__ gstart) {
    int n = blockIdx.x * 256 + threadIdx.x;
    if (n >= NN) return;
    int b = batch[n];
    if (n == 0) {
        for (int g = 0; g <= b; ++g) gstart[g] = 0;
    } else {
        int pb = batch[n - 1];
        if (pb != b)
            for (int g = pb + 1; g <= b; ++g) gstart[g] = n;
    }
    if (n == NN - 1) {
        for (int g = b + 1; g <= NG; ++g) gstart[g] = NN;
    }
}

// ---------------- pooling: bf16 sums into pooled [NG][256] ----------------
__global__ __launch_bounds__(64) void k_pool(const unsigned short* __restrict__ h,
                                             const int* __restrict__ gstart,
                                             unsigned short* __restrict__ pooled) {
    int g = blockIdx.x;
    int lane = threadIdx.x;
    int c0 = lane * 4;
    int beg = gstart[g], end = gstart[g + 1];
    float a0 = 0.f, a1 = 0.f, a2 = 0.f, a3 = 0.f;
    for (int n = beg; n < end; ++n) {
        ushort4 r = *(const ushort4*)&h[(size_t)n * 256 + c0];
        a0 += b2f(r.x); a1 += b2f(r.y); a2 += b2f(r.z); a3 += b2f(r.w);
    }
    ushort4 o;
    o.x = f2b(a0); o.y = f2b(a1); o.z = f2b(a2); o.w = f2b(a3);
    *(ushort4*)&pooled[(size_t)g * 256 + c0] = o;
}

// ---------------- final dot: out[g] = relu(z1[g]) . w2 + b2 ----------------
__global__ __launch_bounds__(256) void k_dot(const float* __restrict__ z1,
                                             const float* __restrict__ w2,
                                             const float* __restrict__ b2,
                                             float* __restrict__ out) {
    int wid = threadIdx.x >> 6, lane = threadIdx.x & 63;
    int g = blockIdx.x * 4 + wid;   // NG % 4 == 0
    float s = fmaxf(z1[(size_t)g * 128 + lane], 0.f) * w2[lane]
            + fmaxf(z1[(size_t)g * 128 + 64 + lane], 0.f) * w2[64 + lane];
#pragma unroll
    for (int off = 32; off; off >>= 1) s += __shfl_xor(s, off);
    if (lane == 0) out[g] = s + b2[0];
}

// ---------------- launch ----------------
extern "C" void kernel_launch(void* const* d_in, const int* in_sizes, int n_in,
                              void* d_out, int out_size, void* d_ws, size_t ws_size,
                              hipStream_t stream) {
    const int* atom_idx   = (const int*)d_in[0];
    const int* degree_idx = (const int*)d_in[1];
    const int* charge_idx = (const int*)d_in[2];
    const int* edge_index = (const int*)d_in[3];
    const int* batch      = (const int*)d_in[4];
    const float* fingerprint = (const float*)d_in[5];
    const float* emb_atom   = (const float*)d_in[6];
    const float* emb_degree = (const float*)d_in[7];
    const float* emb_charge = (const float*)d_in[8];
    const float* proj_w1 = (const float*)d_in[9];
    const float* proj_b1 = (const float*)d_in[10];
    const float* proj_w2 = (const float*)d_in[11];
    const float* proj_b2 = (const float*)d_in[12];
    const float* fp_w = (const float*)d_in[13];
    const float* fp_b = (const float*)d_in[14];
    const float* conv_w[4] = {(const float*)d_in[15], (const float*)d_in[17],
                              (const float*)d_in[19], (const float*)d_in[21]};
    const float* conv_b[4] = {(const float*)d_in[16], (const float*)d_in[18],
                              (const float*)d_in[20], (const float*)d_in[22]};
    const float* lin1_w = (const float*)d_in[23];
    const float* lin1_b = (const float*)d_in[24];
    const float* lin2_w = (const float*)d_in[25];
    const float* lin2_b = (const float*)d_in[26];
    float* out = (float*)d_out;

    const int* src = edge_index;
    const int* dst = edge_index + NE;

    // workspace carve (256B aligned)
    char* p = (char*)d_ws;
    auto carve = [&](size_t bytes) { void* r = (void*)p; p += (bytes + 255) & ~(size_t)255; return r; };
    unsigned short* bufA = (unsigned short*)carve((size_t)NN * 256 * 2);
    unsigned short* bufB = (unsigned short*)carve((size_t)NN * 256 * 2);
    int*   cnt     = (int*)carve((size_t)NN * 4);
    float* dinv    = (float*)carve((size_t)NN * 4);
    int*   row_ptr = (int*)carve((size_t)(NN + 1) * 4);
    int*   cursor  = (int*)carve((size_t)(NN + 1) * 4);
    int*   colA    = (int*)carve((size_t)NE * 4);
    int*   gstart  = (int*)carve((size_t)(NG + 1) * 4);
    int*   bsum    = (int*)carve((size_t)NBLK * 4);
    int*   bpre    = (int*)carve((size_t)NBLK * 4);
    unsigned short* w2t  = (unsigned short*)carve((size_t)128 * 128 * 2);
    unsigned short* cwt[4];
    cwt[0] = (unsigned short*)carve((size_t)256 * 128 * 2);
    for (int l = 1; l < 4; ++l) cwt[l] = (unsigned short*)carve((size_t)256 * 256 * 2);
    unsigned short* l1top = (unsigned short*)carve((size_t)128 * 256 * 2);
    unsigned short* l1bot = (unsigned short*)carve((size_t)128 * 256 * 2);
    unsigned short* fpwbf = (unsigned short*)carve((size_t)2048 * 256 * 2);
    unsigned short* wfpt  = (unsigned short*)carve((size_t)128 * 2048 * 2);
    unsigned short* fpbf  = (unsigned short*)carve((size_t)NG * 2048 * 2);
    unsigned short* pooled = (unsigned short*)carve((size_t)NG * 256 * 2);
    float* Tcat   = (float*)carve((size_t)142 * 128 * 4);
    float* b1p    = (float*)carve((size_t)128 * 4);
    float* z1     = (float*)carve((size_t)NG * 128 * 4);

    // --- CSR build (parallel scan; dinv fused into rowptr) ---
    hipMemsetAsync(cnt, 0, (size_t)NN * 4, stream);
    k_count<<<(NE + 255) / 256, 256, 0, stream>>>(dst, cnt);
    k_bsum<<<NBLK, 256, 0, stream>>>(cnt, bsum);
    k_bscan<<<1, 512, 0, stream>>>(bsum, bpre);
    k_rowptr<<<NBLK, 256, 0, stream>>>(cnt, bpre, row_ptr, cursor, dinv);
    k_fill<<<(NE + 255) / 256, 256, 0, stream>>>(src, dst, cursor, colA);

    // --- fused weight transpose-converts (f32 [K][N] -> bf16 [N][K]) ---
    {
        TArgs a;
        const float* s7[7] = {proj_w2, conv_w[0], conv_w[1], conv_w[2], conv_w[3],
                              lin1_w, lin1_w + 256 * 128};
        unsigned short* d7[7] = {w2t, cwt[0], cwt[1], cwt[2], cwt[3], l1top, l1bot};
        int kn7[7] = {16384, 32768, 65536, 65536, 65536, 32768, 32768};
        int ln7[7] = {7, 8, 8, 8, 8, 7, 7};
        int o = 0;
        for (int s = 0; s < 7; ++s) { a.src[s] = s7[s]; a.dst[s] = d7[s]; a.kn[s] = kn7[s]; a.ln[s] = ln7[s]; a.off[s] = o; o += kn7[s]; }
        a.off[7] = o;   // 311296
        k_prep<<<(o + 255) / 256, 256, 0, stream>>>(a);
    }
    k_cvt<<<(2048 * 256 / 8 + 255) / 256, 256, 0, stream>>>(fp_w, fpwbf, 2048 * 256 / 8);
    k_cvt<<<(NG * 2048 / 8 + 255) / 256, 256, 0, stream>>>(fingerprint, fpbf, NG * 2048 / 8);

    // --- projector tables + fused head bias ---
    k_tab<<<(142 * 128 + 128 + 255) / 256, 256, 0, stream>>>(
        emb_atom, emb_degree, emb_charge, proj_w1, fp_b, lin1_w, lin1_b, Tcat, b1p);

    // --- W_fpT[j][k] = sum_c lin1_w[c][j] * fp_w[k][c]  (bf16 [128][2048]) ---
    k_mmA<false, false, true, false, false><<<dim3(1, 16), 256, 0, stream>>>(
        l1top, fpwbf, wfpt, nullptr, nullptr, 128, 2048, 256, 0);

    // --- projector: h1 = relu(Tcat-gather + b1) -> bufA [NN][128] bf16 ---
    k_emb<<<(NN * 16 + 255) / 256, 256, 0, stream>>>(
        atom_idx, degree_idx, charge_idx, Tcat, proj_b1, bufA);
    // --- h0' = (h1 @ w2 + b2) * dinv -> bufB [NN][128] bf16 (prescaled) ---
    k_mmA<true, false, true, false, true><<<dim3((NN + 127) / 128, 1), 256, 0, stream>>>(
        bufA, w2t, bufB, proj_b2, dinv, NN, 128, 128, 0);

    const int mg = (NN + 127) / 128;  // 782

    // --- layer 0 reordered: agg = (S*h0) -> bufA; h = relu(agg@W0 + b0) -> bufB ---
    k_scat3<1, false><<<NN / 16, 256, 0, stream>>>(bufB, bufA, dinv, row_ptr, colA, nullptr);
    k_mmB<true, true, true, false><<<mg, 512, 0, stream>>>(
        bufA, cwt[0], bufB, conv_b[0], nullptr, NN, 128);

    // --- layers 1-3: xw' = (h@W)*dinv -> bufA; h = relu(S-sum + b) -> bufB ---
    for (int l = 1; l < 4; ++l) {
        k_mmB<false, false, true, true><<<mg, 512, 0, stream>>>(
            bufB, cwt[l], bufA, nullptr, dinv, NN, 256);
        k_scat3<2, true><<<NN / 8, 256, 0, stream>>>(bufA, bufB, dinv, row_ptr, colA, conv_b[l]);
    }

    // --- pooling ---
    k_bounds<<<(NN + 255) / 256, 256, 0, stream>>>(batch, gstart);
    k_pool<<<NG, 64, 0, stream>>>(bufB, gstart, pooled);

    // --- head: z1 = pooled@l1botT + b1p; z1 += fingerprint@W_fpT (split-K); out = relu(z1).w2 + b2 ---
    k_mmA<true, false, false, false, false><<<dim3((NG + 127) / 128, 1), 256, 0, stream>>>(
        pooled, l1bot, z1, b1p, nullptr, NG, 128, 256, 0);
    k_mmA<false, false, false, true, false><<<dim3((NG + 127) / 128, 1, 4), 256, 0, stream>>>(
        fpbf, wfpt, z1, nullptr, nullptr, NG, 128, 2048, 512);
    k_dot<<<NG / 4, 256, 0, stream>>>(z1, lin2_w, lin2_b, out);
}

// Round 11
// 677.417 us; speedup vs baseline: 1.1894x; 1.0059x over previous
//
#include <hip/hip_runtime.h>
#include <stdint.h>

#define NN 100000   // nodes
#define NE 800000   // edges
#define NG 4000     // graphs
#define NBLK ((NN + 255) / 256)   // 391 scan blocks

typedef __attribute__((ext_vector_type(8))) short s16x8;   // 8 bf16 (4 VGPRs)
typedef __attribute__((ext_vector_type(4))) float f32x4;
typedef __attribute__((ext_vector_type(2))) float f32x2;

__device__ __forceinline__ float b2f(unsigned short u) {
    return __uint_as_float(((unsigned int)u) << 16);
}
__device__ __forceinline__ unsigned short f2b(float f) {
    unsigned int x = __float_as_uint(f);
    x = x + 0x7FFFu + ((x >> 16) & 1u);   // RNE
    return (unsigned short)(x >> 16);
}
__device__ __forceinline__ s16x8 cvt8(const float* __restrict__ p) {
    float4 a = *(const float4*)p;
    float4 b = *(const float4*)(p + 4);
    s16x8 r = {(short)f2b(a.x), (short)f2b(a.y), (short)f2b(a.z), (short)f2b(a.w),
               (short)f2b(b.x), (short)f2b(b.y), (short)f2b(b.z), (short)f2b(b.w)};
    return r;
}

// async global->LDS, 16B per lane. LDS dest = wave-uniform base + lane*16.
__device__ __forceinline__ void gload16(const void* g, void* l) {
    __builtin_amdgcn_global_load_lds((const __attribute__((address_space(1))) unsigned int*)g,
                                     (__attribute__((address_space(3))) unsigned int*)l, 16, 0, 0);
}

// accumulate 8 bf16 into 4 f32 pairs via v_pk_add_f32 (2 adds/inst)
__device__ __forceinline__ void acc8(f32x2* acc, s16x8 r) {
    const unsigned int* u = (const unsigned int*)&r;
#pragma unroll
    for (int q = 0; q < 4; ++q) {
        unsigned int w = u[q];
        f32x2 x;
        x[0] = __uint_as_float(w << 16);          // even col (low bf16)
        x[1] = __uint_as_float(w & 0xFFFF0000u);  // odd col (high bf16)
        asm("v_pk_add_f32 %0, %1, %0" : "+v"(acc[q]) : "v"(x));
    }
}

// ---------------- degree / CSR build ----------------
__global__ void k_count(const int* __restrict__ dst, int* __restrict__ cnt) {
    int e = blockIdx.x * 256 + threadIdx.x;
    if (e < NE) atomicAdd(&cnt[dst[e]], 1);
}

__global__ __launch_bounds__(256) void k_bsum(const int* __restrict__ cnt, int* __restrict__ bsum) {
    __shared__ int s[256];
    int i = blockIdx.x * 256 + threadIdx.x;
    s[threadIdx.x] = (i < NN) ? cnt[i] : 0;
    __syncthreads();
    for (int off = 128; off; off >>= 1) {
        if (threadIdx.x < off) s[threadIdx.x] += s[threadIdx.x + off];
        __syncthreads();
    }
    if (threadIdx.x == 0) bsum[blockIdx.x] = s[0];
}

__global__ __launch_bounds__(512) void k_bscan(const int* __restrict__ bsum, int* __restrict__ bpre) {
    __shared__ int s[512];
    int t = threadIdx.x;
    int v = (t < NBLK) ? bsum[t] : 0;
    s[t] = v;
    __syncthreads();
    for (int off = 1; off < 512; off <<= 1) {
        int u = (t >= off) ? s[t - off] : 0;
        __syncthreads();
        s[t] += u;
        __syncthreads();
    }
    if (t < NBLK) bpre[t] = s[t] - v;   // exclusive prefix of block sums
}

// row_ptr + cursor + dinv in one pass
__global__ __launch_bounds__(256) void k_rowptr(const int* __restrict__ cnt, const int* __restrict__ bpre,
                                                int* __restrict__ row_ptr, int* __restrict__ cursor,
                                                float* __restrict__ dinv) {
    __shared__ int s[256];
    int t = threadIdx.x;
    int i = blockIdx.x * 256 + t;
    int v = (i < NN) ? cnt[i] : 0;
    s[t] = v;
    __syncthreads();
    for (int off = 1; off < 256; off <<= 1) {
        int u = (t >= off) ? s[t - off] : 0;
        __syncthreads();
        s[t] += u;
        __syncthreads();
    }
    if (i < NN) {
        int excl = bpre[blockIdx.x] + s[t] - v;
        row_ptr[i] = excl;
        cursor[i] = excl;
        dinv[i] = rsqrtf((float)(v + 1));   // +1 self loop
        if (i == NN - 1) row_ptr[NN] = NE;
    }
}

__global__ void k_fill(const int* __restrict__ src, const int* __restrict__ dst,
                       int* __restrict__ cursor, int* __restrict__ colA) {
    int e = blockIdx.x * 256 + threadIdx.x;
    if (e < NE) {
        int d = dst[e];
        int p = atomicAdd(&cursor[d], 1);
        colA[p] = src[e];
    }
}

// ---------------- fused weight transpose-convert: 7 segments, f32 [K][N] -> bf16 [N][K] ----------------
struct TArgs {
    const float* src[7];
    unsigned short* dst[7];
    int kn[7];
    int ln[7];
    int off[8];   // prefix offsets, off[7] = total
};

__global__ __launch_bounds__(256) void k_prep(TArgs a) {
    int i = blockIdx.x * 256 + threadIdx.x;
    if (i >= a.off[7]) return;
    int s = 0;
    while (i >= a.off[s + 1]) ++s;
    int j = i - a.off[s];
    int k = j >> a.ln[s], n = j & ((1 << a.ln[s]) - 1);
    a.dst[s][(size_t)n * (a.kn[s] >> a.ln[s]) + k] = f2b(a.src[s][j]);
}

// two-segment f32 -> bf16 convert (no transpose), 8 elems/thread
__global__ void k_cvt2(const float* __restrict__ s0, unsigned short* __restrict__ d0, int n80,
                       const float* __restrict__ s1, unsigned short* __restrict__ d1, int n81) {
    int i = blockIdx.x * 256 + threadIdx.x;
    if (i < n80) {
        *(s16x8*)&d0[(size_t)i * 8] = cvt8(&s0[(size_t)i * 8]);
    } else if (i < n80 + n81) {
        int j = i - n80;
        *(s16x8*)&d1[(size_t)j * 8] = cvt8(&s1[(size_t)j * 8]);
    }
}

// ---------------- projector linearization: Tcat[142][128] + fused head bias b1p ----------------
// Tcat rows 0..119 = ea@W1[0:128], 120..131 = ed@W1[128:256],
// 132..141 = ec@W1[256:384] + proj_b1 (bias folded into charge rows).
// b1p[j] = lin1_b[j] + sum_c fp_b[c]*lin1_w[c][j]
__global__ __launch_bounds__(256) void k_tab(const float* __restrict__ ea, const float* __restrict__ ed,
                                             const float* __restrict__ ec, const float* __restrict__ w1,
                                             const float* __restrict__ pb1,
                                             const float* __restrict__ fpb, const float* __restrict__ l1w,
                                             const float* __restrict__ l1b,
                                             float* __restrict__ Tcat, float* __restrict__ b1p) {
    int i = blockIdx.x * 256 + threadIdx.x;
    if (i < 142 * 128) {
        int r = i >> 7, j = i & 127;
        const float* src; int off, lr;
        if (r < 120)      { src = ea; off = 0;   lr = r; }
        else if (r < 132) { src = ed; off = 128; lr = r - 120; }
        else              { src = ec; off = 256; lr = r - 132; }
        float s = (r >= 132) ? pb1[j] : 0.f;
        for (int k = 0; k < 128; ++k)
            s = fmaf(src[lr * 128 + k], w1[(off + k) * 128 + j], s);
        Tcat[i] = s;
    } else if (i < 142 * 128 + 128) {
        int j = i - 142 * 128;
        float s = l1b[j];
        for (int c = 0; c < 256; ++c)
            s = fmaf(fpb[c], l1w[c * 128 + j], s);
        b1p[j] = s;
    }
}

// ---------------- fused projector GEMM: C = (relu(Tcat-gather) @ w2t + b2) * dinv, bf16 ----------------
// M=NN, N=128, K=128. A staged on-the-fly from L2-hot Tcat (b1 pre-folded into charge rows).
__global__ __launch_bounds__(256) void k_mmE(
    const int* __restrict__ ai, const int* __restrict__ di, const int* __restrict__ ci,
    const float* __restrict__ Tcat, const unsigned short* __restrict__ Bt,
    unsigned short* __restrict__ C, const float* __restrict__ bias,
    const float* __restrict__ dinv) {
    __shared__ unsigned short As[128 * 40];   // stride 40: 2-way bank alias = free
    __shared__ unsigned short Bs[128 * 40];
    const int tid = threadIdx.x;
    const int row0 = blockIdx.x * 128;
    const int lane = tid & 63, wid = tid >> 6;
    const int wrow = (wid >> 1) * 64, wcol = (wid & 1) * 64;
    const int lr = lane & 15, lk8 = (lane >> 4) * 8;
    const int sr = tid >> 1, skc = (tid & 1) * 16;
    const int row = row0 + sr;
    const int rr = min(row, NN - 1);
    const float* ta = Tcat + ai[rr] * 128;
    const float* td = Tcat + (120 + di[rr]) * 128;
    const float* tc = Tcat + (132 + ci[rr]) * 128;

    f32x4 acc[4][4] = {};

    for (int kb = 0; kb < 128; kb += 32) {
        if (kb) __syncthreads();
#pragma unroll
        for (int c = 0; c < 2; ++c) {
            int kg = skc + c * 8;
            int k = kb + kg;
            float4 a0 = *(const float4*)&ta[k], a1 = *(const float4*)&ta[k + 4];
            float4 d0 = *(const float4*)&td[k], d1 = *(const float4*)&td[k + 4];
            float4 e0 = *(const float4*)&tc[k], e1 = *(const float4*)&tc[k + 4];
            unsigned short o[8];
            o[0] = f2b(fmaxf(a0.x + d0.x + e0.x, 0.f));
            o[1] = f2b(fmaxf(a0.y + d0.y + e0.y, 0.f));
            o[2] = f2b(fmaxf(a0.z + d0.z + e0.z, 0.f));
            o[3] = f2b(fmaxf(a0.w + d0.w + e0.w, 0.f));
            o[4] = f2b(fmaxf(a1.x + d1.x + e1.x, 0.f));
            o[5] = f2b(fmaxf(a1.y + d1.y + e1.y, 0.f));
            o[6] = f2b(fmaxf(a1.z + d1.z + e1.z, 0.f));
            o[7] = f2b(fmaxf(a1.w + d1.w + e1.w, 0.f));
            *(s16x8*)&As[sr * 40 + kg] = *(const s16x8*)o;
            s16x8 w = *(const s16x8*)&Bt[(size_t)sr * 128 + k];
            *(s16x8*)&Bs[sr * 40 + kg] = w;
        }
        __syncthreads();
        s16x8 af[4], bfr[4];
#pragma unroll
        for (int f = 0; f < 4; ++f)
            af[f] = *(const s16x8*)&As[(wrow + f * 16 + lr) * 40 + lk8];
#pragma unroll
        for (int f = 0; f < 4; ++f)
            bfr[f] = *(const s16x8*)&Bs[(wcol + f * 16 + lr) * 40 + lk8];
#pragma unroll
        for (int fm = 0; fm < 4; ++fm)
#pragma unroll
            for (int fn = 0; fn < 4; ++fn)
                acc[fm][fn] = __builtin_amdgcn_mfma_f32_16x16x32_bf16(af[fm], bfr[fn], acc[fm][fn], 0, 0, 0);
    }
#pragma unroll
    for (int fm = 0; fm < 4; ++fm) {
#pragma unroll
        for (int r = 0; r < 4; ++r) {
            int orow = row0 + wrow + fm * 16 + (lane >> 4) * 4 + r;
            if (orow < NN) {
                float pr = dinv[orow];
#pragma unroll
                for (int fn = 0; fn < 4; ++fn) {
                    int col = wcol + fn * 16 + lr;
                    float v = (acc[fm][fn][r] + bias[col]) * pr;
                    C[(size_t)orow * 128 + col] = f2b(v);
                }
            }
        }
    }
}

// ---------------- 2-phase double-buffered MFMA GEMM, tile 128x128 ----------------
template <bool BIAS, bool RELU, bool CBF16, bool SPLITK, bool PRES>
__global__ __launch_bounds__(256) void k_mmA(
    const unsigned short* __restrict__ A, const unsigned short* __restrict__ Bt,
    void* __restrict__ Cv, const float* __restrict__ bias, const float* __restrict__ pres,
    int M, int N, int K, int kc) {
    __shared__ unsigned short As[2][128 * 32];
    __shared__ unsigned short Bs[2][128 * 32];
    const int tid = threadIdx.x;
    const int row0 = blockIdx.x * 128, col0 = blockIdx.y * 128;
    const int lane = tid & 63, wid = tid >> 6;
    const int wrow = (wid >> 1) * 64, wcol = (wid & 1) * 64;
    const int lr = lane & 15, lk8 = (lane >> 4) * 8;

    const int k0 = SPLITK ? blockIdx.z * kc : 0;
    const int nt = (SPLITK ? kc : K) / 32;

    const int sra = wid * 32 + (lane >> 2);
    const int sca = (lane & 3) * 8;
    const unsigned short* a0 = A + (size_t)min(row0 + sra, M - 1) * K + sca + k0;
    const unsigned short* a1 = A + (size_t)min(row0 + sra + 16, M - 1) * K + sca + k0;
    const unsigned short* b0 = Bt + (size_t)(col0 + sra) * K + sca + k0;
    const unsigned short* b1 = Bt + (size_t)(col0 + sra + 16) * K + sca + k0;
    const int lo0 = (wid * 2 + 0) * 512;
    const int lo1 = (wid * 2 + 1) * 512;

    f32x4 acc[4][4] = {};

    gload16(a0, &As[0][lo0]);
    gload16(a1, &As[0][lo1]);
    gload16(b0, &Bs[0][lo0]);
    gload16(b1, &Bs[0][lo1]);
    __syncthreads();

    int cur = 0;
    for (int t = 0; t < nt; ++t) {
        if (t + 1 < nt) {
            int kb = (t + 1) * 32;
            gload16(a0 + kb, &As[cur ^ 1][lo0]);
            gload16(a1 + kb, &As[cur ^ 1][lo1]);
            gload16(b0 + kb, &Bs[cur ^ 1][lo0]);
            gload16(b1 + kb, &Bs[cur ^ 1][lo1]);
        }
        s16x8 af[4], bfr[4];
#pragma unroll
        for (int f = 0; f < 4; ++f)
            af[f] = *(const s16x8*)&As[cur][(wrow + f * 16 + lr) * 32 + lk8];
#pragma unroll
        for (int f = 0; f < 4; ++f)
            bfr[f] = *(const s16x8*)&Bs[cur][(wcol + f * 16 + lr) * 32 + lk8];
#pragma unroll
        for (int fm = 0; fm < 4; ++fm)
#pragma unroll
            for (int fn = 0; fn < 4; ++fn)
                acc[fm][fn] = __builtin_amdgcn_mfma_f32_16x16x32_bf16(af[fm], bfr[fn], acc[fm][fn], 0, 0, 0);
        __syncthreads();
        cur ^= 1;
    }
#pragma unroll
    for (int fm = 0; fm < 4; ++fm) {
#pragma unroll
        for (int r = 0; r < 4; ++r) {
            int row = row0 + wrow + fm * 16 + (lane >> 4) * 4 + r;
            if (row < M) {
                float pr = PRES ? pres[row] : 1.f;
#pragma unroll
                for (int fn = 0; fn < 4; ++fn) {
                    int col = col0 + wcol + fn * 16 + lr;
                    float v = acc[fm][fn][r];
                    if (SPLITK) {
                        atomicAdd(&((float*)Cv)[(size_t)row * N + col], v);
                    } else {
                        if (BIAS) v += bias[col];
                        if (RELU) v = fmaxf(v, 0.f);
                        if (PRES) v *= pr;
                        if (CBF16) ((unsigned short*)Cv)[(size_t)row * N + col] = f2b(v);
                        else       ((float*)Cv)[(size_t)row * N + col] = v;
                    }
                }
            }
        }
    }
}

// ---------------- 2-phase dbuf MFMA GEMM, tile 128x256 (N==256 exactly) ----------------
template <bool BIAS, bool RELU, bool CBF16, bool PRES>
__global__ __launch_bounds__(512) void k_mmB(
    const unsigned short* __restrict__ A, const unsigned short* __restrict__ Bt,
    void* __restrict__ Cv, const float* __restrict__ bias, const float* __restrict__ pres,
    int M, int K) {
    constexpr int N = 256;
    __shared__ unsigned short As[2][128 * 32];
    __shared__ unsigned short Bs[2][256 * 32];
    const int tid = threadIdx.x;
    const int row0 = blockIdx.x * 128;
    const int lane = tid & 63, wid = tid >> 6;          // wid 0..7
    const int wrow = (wid >> 2) * 64, wcol = (wid & 3) * 64;
    const int lr = lane & 15, lk8 = (lane >> 4) * 8;

    const int nt = K / 32;

    const int rsub = lane >> 2;        // 0..15
    const int csub = (lane & 3) * 8;
    const unsigned short* ga  = A  + (size_t)min(row0 + wid * 16 + rsub, M - 1) * K + csub;
    const unsigned short* gb0 = Bt + (size_t)(wid * 16 + rsub) * K + csub;
    const unsigned short* gb1 = Bt + (size_t)(128 + wid * 16 + rsub) * K + csub;
    const int la  = wid * 512;
    const int lb0 = wid * 512;
    const int lb1 = (8 + wid) * 512;

    f32x4 acc[4][4] = {};

    gload16(ga, &As[0][la]);
    gload16(gb0, &Bs[0][lb0]);
    gload16(gb1, &Bs[0][lb1]);
    __syncthreads();

    int cur = 0;
    for (int t = 0; t < nt; ++t) {
        if (t + 1 < nt) {
            int kb = (t + 1) * 32;
            gload16(ga + kb, &As[cur ^ 1][la]);
            gload16(gb0 + kb, &Bs[cur ^ 1][lb0]);
            gload16(gb1 + kb, &Bs[cur ^ 1][lb1]);
        }
        s16x8 af[4], bfr[4];
#pragma unroll
        for (int f = 0; f < 4; ++f)
            af[f] = *(const s16x8*)&As[cur][(wrow + f * 16 + lr) * 32 + lk8];
#pragma unroll
        for (int f = 0; f < 4; ++f)
            bfr[f] = *(const s16x8*)&Bs[cur][(wcol + f * 16 + lr) * 32 + lk8];
#pragma unroll
        for (int fm = 0; fm < 4; ++fm)
#pragma unroll
            for (int fn = 0; fn < 4; ++fn)
                acc[fm][fn] = __builtin_amdgcn_mfma_f32_16x16x32_bf16(af[fm], bfr[fn], acc[fm][fn], 0, 0, 0);
        __syncthreads();
        cur ^= 1;
    }
#pragma unroll
    for (int fm = 0; fm < 4; ++fm) {
#pragma unroll
        for (int r = 0; r < 4; ++r) {
            int row = row0 + wrow + fm * 16 + (lane >> 4) * 4 + r;
            if (row < M) {
                float pr = PRES ? pres[row] : 1.f;
#pragma unroll
                for (int fn = 0; fn < 4; ++fn) {
                    int col = wcol + fn * 16 + lr;
                    float v = acc[fm][fn][r];
                    if (BIAS) v += bias[col];
                    if (RELU) v = fmaxf(v, 0.f);
                    if (PRES) v *= pr;
                    if (CBF16) ((unsigned short*)Cv)[(size_t)row * N + col] = f2b(v);
                    else       ((float*)Cv)[(size_t)row * N + col] = v;
                }
            }
        }
    }
}

// ---------------- GCN aggregate on dinv-PRESCALED rows, group-per-node, unroll 4 ----------------
template <int WPN, bool FUSE>
__global__ __launch_bounds__(256) void k_scat3(const unsigned short* __restrict__ xw,
                                               unsigned short* __restrict__ hout,
                                               const float* __restrict__ dinv,
                                               const int* __restrict__ row_ptr,
                                               const int* __restrict__ colA,
                                               const float* __restrict__ bias) {
    constexpr int W = WPN * 128;     // feature width
    constexpr int NPW = 4 / WPN;     // nodes per wave
    const int wid = threadIdx.x >> 6, lane = threadIdx.x & 63;
    const int grp = lane >> 4, li = lane & 15;
    const int v = (blockIdx.x * 4 + wid) * NPW + grp / WPN;
    const int cs = (WPN == 2) ? (grp & 1) * 128 : 0;
    const int c0 = cs + li * 8;

    const float dv = dinv[v];
    s16x8 rs = *(const s16x8*)&xw[(size_t)v * W + c0];   // self (prescaled)

    f32x2 acc[4] = {};
    const int beg = row_ptr[v], end = row_ptr[v + 1];
    int p = beg;
    for (; p + 3 < end; p += 4) {
        int s0 = colA[p], s1 = colA[p + 1], s2 = colA[p + 2], s3 = colA[p + 3];
        s16x8 r0 = *(const s16x8*)&xw[(size_t)s0 * W + c0];
        s16x8 r1 = *(const s16x8*)&xw[(size_t)s1 * W + c0];
        s16x8 r2 = *(const s16x8*)&xw[(size_t)s2 * W + c0];
        s16x8 r3 = *(const s16x8*)&xw[(size_t)s3 * W + c0];
        acc8(acc, r0);
        acc8(acc, r1);
        acc8(acc, r2);
        acc8(acc, r3);
    }
    for (; p < end; ++p) {
        s16x8 r0 = *(const s16x8*)&xw[(size_t)colA[p] * W + c0];
        acc8(acc, r0);
    }

    unsigned short o[8];
#pragma unroll
    for (int j = 0; j < 8; ++j) {
        float a = acc[j >> 1][j & 1];
        a += b2f((unsigned short)rs[j]);
        a *= dv;
        if (FUSE) a = fmaxf(a + bias[c0 + j], 0.f);
        o[j] = f2b(a);
    }
    *(s16x8*)&hout[(size_t)v * W + c0] = *(const s16x8*)o;
}

// ---------------- pooling with inline graph-boundary binary search ----------------
__global__ __launch_bounds__(64) void k_pool2(const unsigned short* __restrict__ h,
                                              const int* __restrict__ batch,
                                              unsigned short* __restrict__ pooled) {
    __shared__ int sb[2];
    int g = blockIdx.x;
    if (threadIdx.x < 2) {
        int target = g + threadIdx.x;
        int lo = 0, hi = NN;             // first n with batch[n] >= target
        while (lo < hi) {
            int mid = (lo + hi) >> 1;
            if (batch[mid] < target) lo = mid + 1; else hi = mid;
        }
        sb[threadIdx.x] = lo;
    }
    __syncthreads();
    int beg = sb[0], end = sb[1];
    int lane = threadIdx.x;
    int c0 = lane * 4;
    float a0 = 0.f, a1 = 0.f, a2 = 0.f, a3 = 0.f;
    for (int n = beg; n < end; ++n) {
        ushort4 r = *(const ushort4*)&h[(size_t)n * 256 + c0];
        a0 += b2f(r.x); a1 += b2f(r.y); a2 += b2f(r.z); a3 += b2f(r.w);
    }
    ushort4 o;
    o.x = f2b(a0); o.y = f2b(a1); o.z = f2b(a2); o.w = f2b(a3);
    *(ushort4*)&pooled[(size_t)g * 256 + c0] = o;
}

// ---------------- final dot: out[g] = relu(z1[g]) . w2 + b2 ----------------
__global__ __launch_bounds__(256) void k_dot(const float* __restrict__ z1,
                                             const float* __restrict__ w2,
                                             const float* __restrict__ b2,
                                             float* __restrict__ out) {
    int wid = threadIdx.x >> 6, lane = threadIdx.x & 63;
    int g = blockIdx.x * 4 + wid;   // NG % 4 == 0
    float s = fmaxf(z1[(size_t)g * 128 + lane], 0.f) * w2[lane]
            + fmaxf(z1[(size_t)g * 128 + 64 + lane], 0.f) * w2[64 + lane];
#pragma unroll
    for (int off = 32; off; off >>= 1) s += __shfl_xor(s, off);
    if (lane == 0) out[g] = s + b2[0];
}

// ---------------- launch ----------------
extern "C" void kernel_launch(void* const* d_in, const int* in_sizes, int n_in,
                              void* d_out, int out_size, void* d_ws, size_t ws_size,
                              hipStream_t stream) {
    const int* atom_idx   = (const int*)d_in[0];
    const int* degree_idx = (const int*)d_in[1];
    const int* charge_idx = (const int*)d_in[2];
    const int* edge_index = (const int*)d_in[3];
    const int* batch      = (const int*)d_in[4];
    const float* fingerprint = (const float*)d_in[5];
    const float* emb_atom   = (const float*)d_in[6];
    const float* emb_degree = (const float*)d_in[7];
    const float* emb_charge = (const float*)d_in[8];
    const float* proj_w1 = (const float*)d_in[9];
    const float* proj_b1 = (const float*)d_in[10];
    const float* proj_w2 = (const float*)d_in[11];
    const float* proj_b2 = (const float*)d_in[12];
    const float* fp_w = (const float*)d_in[13];
    const float* fp_b = (const float*)d_in[14];
    const float* conv_w[4] = {(const float*)d_in[15], (const float*)d_in[17],
                              (const float*)d_in[19], (const float*)d_in[21]};
    const float* conv_b[4] = {(const float*)d_in[16], (const float*)d_in[18],
                              (const float*)d_in[20], (const float*)d_in[22]};
    const float* lin1_w = (const float*)d_in[23];
    const float* lin1_b = (const float*)d_in[24];
    const float* lin2_w = (const float*)d_in[25];
    const float* lin2_b = (const float*)d_in[26];
    float* out = (float*)d_out;

    const int* src = edge_index;
    const int* dst = edge_index + NE;

    // workspace carve (256B aligned)
    char* p = (char*)d_ws;
    auto carve = [&](size_t bytes) { void* r = (void*)p; p += (bytes + 255) & ~(size_t)255; return r; };
    unsigned short* bufA = (unsigned short*)carve((size_t)NN * 256 * 2);
    unsigned short* bufB = (unsigned short*)carve((size_t)NN * 256 * 2);
    int*   cnt     = (int*)carve((size_t)NN * 4);
    float* dinv    = (float*)carve((size_t)NN * 4);
    int*   row_ptr = (int*)carve((size_t)(NN + 1) * 4);
    int*   cursor  = (int*)carve((size_t)(NN + 1) * 4);
    int*   colA    = (int*)carve((size_t)NE * 4);
    int*   bsum    = (int*)carve((size_t)NBLK * 4);
    int*   bpre    = (int*)carve((size_t)NBLK * 4);
    unsigned short* w2t  = (unsigned short*)carve((size_t)128 * 128 * 2);
    unsigned short* cwt[4];
    cwt[0] = (unsigned short*)carve((size_t)256 * 128 * 2);
    for (int l = 1; l < 4; ++l) cwt[l] = (unsigned short*)carve((size_t)256 * 256 * 2);
    unsigned short* l1top = (unsigned short*)carve((size_t)128 * 256 * 2);
    unsigned short* l1bot = (unsigned short*)carve((size_t)128 * 256 * 2);
    unsigned short* fpwbf = (unsigned short*)carve((size_t)2048 * 256 * 2);
    unsigned short* wfpt  = (unsigned short*)carve((size_t)128 * 2048 * 2);
    unsigned short* fpbf  = (unsigned short*)carve((size_t)NG * 2048 * 2);
    unsigned short* pooled = (unsigned short*)carve((size_t)NG * 256 * 2);
    float* Tcat   = (float*)carve((size_t)142 * 128 * 4);
    float* b1p    = (float*)carve((size_t)128 * 4);
    float* z1     = (float*)carve((size_t)NG * 128 * 4);

    // --- CSR build (parallel scan; dinv fused into rowptr) ---
    hipMemsetAsync(cnt, 0, (size_t)NN * 4, stream);
    k_count<<<(NE + 255) / 256, 256, 0, stream>>>(dst, cnt);
    k_bsum<<<NBLK, 256, 0, stream>>>(cnt, bsum);
    k_bscan<<<1, 512, 0, stream>>>(bsum, bpre);
    k_rowptr<<<NBLK, 256, 0, stream>>>(cnt, bpre, row_ptr, cursor, dinv);
    k_fill<<<(NE + 255) / 256, 256, 0, stream>>>(src, dst, cursor, colA);

    // --- fused weight transpose-converts (f32 [K][N] -> bf16 [N][K]) ---
    {
        TArgs a;
        const float* s7[7] = {proj_w2, conv_w[0], conv_w[1], conv_w[2], conv_w[3],
                              lin1_w, lin1_w + 256 * 128};
        unsigned short* d7[7] = {w2t, cwt[0], cwt[1], cwt[2], cwt[3], l1top, l1bot};
        int kn7[7] = {16384, 32768, 65536, 65536, 65536, 32768, 32768};
        int ln7[7] = {7, 8, 8, 8, 8, 7, 7};
        int o = 0;
        for (int s = 0; s < 7; ++s) { a.src[s] = s7[s]; a.dst[s] = d7[s]; a.kn[s] = kn7[s]; a.ln[s] = ln7[s]; a.off[s] = o; o += kn7[s]; }
        a.off[7] = o;
        k_prep<<<(o + 255) / 256, 256, 0, stream>>>(a);
    }
    {
        int n80 = 2048 * 256 / 8, n81 = NG * 2048 / 8;
        k_cvt2<<<(n80 + n81 + 255) / 256, 256, 0, stream>>>(fp_w, fpwbf, n80, fingerprint, fpbf, n81);
    }

    // --- projector tables (+proj_b1 folded) + fused head bias ---
    k_tab<<<(142 * 128 + 128 + 255) / 256, 256, 0, stream>>>(
        emb_atom, emb_degree, emb_charge, proj_w1, proj_b1, fp_b, lin1_w, lin1_b, Tcat, b1p);

    // --- W_fpT[j][k] = sum_c lin1_w[c][j] * fp_w[k][c]  (bf16 [128][2048]) ---
    k_mmA<false, false, true, false, false><<<dim3(1, 16), 256, 0, stream>>>(
        l1top, fpwbf, wfpt, nullptr, nullptr, 128, 2048, 256, 0);

    const int mg = (NN + 127) / 128;  // 782

    // --- fused projector: h0' = (relu(Tcat-gather) @ w2 + b2) * dinv -> bufB ---
    k_mmE<<<mg, 256, 0, stream>>>(atom_idx, degree_idx, charge_idx, Tcat, w2t, bufB, proj_b2, dinv);

    // --- layer 0 reordered: agg = (S*h0) -> bufA; h = relu(agg@W0 + b0) -> bufB ---
    k_scat3<1, false><<<NN / 16, 256, 0, stream>>>(bufB, bufA, dinv, row_ptr, colA, nullptr);
    k_mmB<true, true, true, false><<<mg, 512, 0, stream>>>(
        bufA, cwt[0], bufB, conv_b[0], nullptr, NN, 128);

    // --- layers 1-3: xw' = (h@W)*dinv -> bufA; h = relu(S-sum + b) -> bufB ---
    for (int l = 1; l < 4; ++l) {
        k_mmB<false, false, true, true><<<mg, 512, 0, stream>>>(
            bufB, cwt[l], bufA, nullptr, dinv, NN, 256);
        k_scat3<2, true><<<NN / 8, 256, 0, stream>>>(bufA, bufB, dinv, row_ptr, colA, conv_b[l]);
    }

    // --- pooling (boundaries via binary search on sorted batch) ---
    k_pool2<<<NG, 64, 0, stream>>>(bufB, batch, pooled);

    // --- head: z1 = pooled@l1botT + b1p; z1 += fingerprint@W_fpT (split-K); out = relu(z1).w2 + b2 ---
    k_mmA<true, false, false, false, false><<<dim3((NG + 127) / 128, 1), 256, 0, stream>>>(
        pooled, l1bot, z1, b1p, nullptr, NG, 128, 256, 0);
    k_mmA<false, false, false, true, false><<<dim3((NG + 127) / 128, 1, 4), 256, 0, stream>>>(
        fpbf, wfpt, z1, nullptr, nullptr, NG, 128, 2048, 512);
    k_dot<<<NG / 4, 256, 0, stream>>>(z1, lin2_w, lin2_b, out);
}